// Round 8
// baseline (846.952 us; speedup 1.0000x reference)
//
#include <hip/hip_runtime.h>
#include <cstdint>

// Model dims (fixed): L=128, B=64, DM=1024, H=256, F=512, HID=256, MEM=768,
// N=B*L=8192, NC=6, R=8, NB=30, WIN=10

typedef __attribute__((ext_vector_type(8))) short bf16x8;
typedef __attribute__((ext_vector_type(4))) float f32x4;

// ---------------------------------------------------------------------------
// bf16 NT MFMA GEMM: C(MxN) = A(MxK)bf16 @ Bt(NxK)bf16^T (+bias)(+accum)
// C is f32, or bf16 when OUTBF. Batched via blockIdx.z (sA/sB/sC/sBias elem
// strides). 128x128x32 tile, 4 waves (2x2), 16x16x32 MFMA, 4x4 frags/wave.
// ---------------------------------------------------------------------------
template<bool HASBIAS, bool ACCUM, bool RELU, bool OUTBF>
__global__ __launch_bounds__(256) void gemm_bf16_nt(
    const ushort* __restrict__ A, const ushort* __restrict__ Bt,
    const float* __restrict__ bias, void* __restrict__ Cv,
    int M, int N, int K, long sA, long sB, long sC, long sBias)
{
  const int bz = blockIdx.z;
  A += (long)bz * sA;
  Bt += (long)bz * sB;
  if (HASBIAS) bias += (long)bz * sBias;
  float*  Cf = OUTBF ? nullptr : ((float*)Cv + (long)bz * sC);
  ushort* Cb = OUTBF ? ((ushort*)Cv + (long)bz * sC) : nullptr;

  const int bn = blockIdx.x * 128, bm = blockIdx.y * 128;

  __shared__ ushort As[128][40];   // +8 pad: benign 2-way bank aliasing
  __shared__ ushort Bs[128][40];

  const int tid = threadIdx.x;
  const int wave = tid >> 6, lane = tid & 63;
  const int wm = (wave >> 1) * 64, wn = (wave & 1) * 64;
  const int fr = lane & 15;
  const int fk = (lane >> 4) * 8;

  f32x4 acc[4][4];
#pragma unroll
  for (int i = 0; i < 4; ++i)
#pragma unroll
    for (int j = 0; j < 4; ++j) acc[i][j] = (f32x4){0.f, 0.f, 0.f, 0.f};

  const int sr = tid >> 1;
  const int sq = (tid & 1) * 16;

  for (int k0 = 0; k0 < K; k0 += 32) {
    const uint4* ga = (const uint4*)(A + (long)(bm + sr) * K + k0 + sq);
    uint4 av0 = ga[0], av1 = ga[1];
    const uint4* gb = (const uint4*)(Bt + (long)(bn + sr) * K + k0 + sq);
    uint4 bv0 = gb[0], bv1 = gb[1];
    *(uint4*)&As[sr][sq] = av0;
    *(uint4*)&As[sr][sq + 8] = av1;
    *(uint4*)&Bs[sr][sq] = bv0;
    *(uint4*)&Bs[sr][sq + 8] = bv1;
    __syncthreads();

    bf16x8 af[4], bfr[4];
#pragma unroll
    for (int f = 0; f < 4; ++f) {
      af[f]  = *(const bf16x8*)&As[wm + f * 16 + fr][fk];
      bfr[f] = *(const bf16x8*)&Bs[wn + f * 16 + fr][fk];
    }
#pragma unroll
    for (int mf = 0; mf < 4; ++mf)
#pragma unroll
      for (int nf = 0; nf < 4; ++nf)
        acc[mf][nf] = __builtin_amdgcn_mfma_f32_16x16x32_bf16(
            af[mf], bfr[nf], acc[mf][nf], 0, 0, 0);
    __syncthreads();
  }

  float bv[4];
#pragma unroll
  for (int nf = 0; nf < 4; ++nf)
    bv[nf] = HASBIAS ? bias[bn + wn + nf * 16 + fr] : 0.f;

  const int crow0 = (lane >> 4) * 4;
#pragma unroll
  for (int mf = 0; mf < 4; ++mf)
#pragma unroll
    for (int r = 0; r < 4; ++r) {
      const long roff = (long)(bm + wm + mf * 16 + crow0 + r) * N + bn + wn;
#pragma unroll
      for (int nf = 0; nf < 4; ++nf) {
        float v = acc[mf][nf][r] + bv[nf];
        if (OUTBF) {
          unsigned u = __float_as_uint(v);
          u += 0x7fffu + ((u >> 16) & 1u);
          Cb[roff + nf * 16 + fr] = (ushort)(u >> 16);
        } else {
          if (ACCUM) v += Cf[roff + nf * 16 + fr];
          if (RELU) v = fmaxf(v, 0.f);
          Cf[roff + nf * 16 + fr] = v;
        }
      }
    }
}

// ---------------------------------------------------------------------------
// helpers
// ---------------------------------------------------------------------------
__device__ __forceinline__ unsigned short f2bf(float f) {
  unsigned u = __float_as_uint(f);
  u += 0x7fffu + ((u >> 16) & 1u);
  return (unsigned short)(u >> 16);
}
__device__ __forceinline__ float fast_sig(float x) {
  return __builtin_amdgcn_rcpf(1.f + __expf(-x));
}
__device__ __forceinline__ float fast_tanh(float x) {
  // tanh(x) = 2*sigmoid(2x) - 1
  return 2.f * fast_sig(2.f * x) - 1.f;
}

__device__ __forceinline__ int sdot4_(uint a, uint b, int c) {
#if __has_builtin(__builtin_amdgcn_sdot4)
  return __builtin_amdgcn_sdot4((int)a, (int)b, c, false);
#else
  int r = c;
  r += ((int)(a << 24) >> 24) * ((int)(b << 24) >> 24);
  r += ((int)(a << 16) >> 24) * ((int)(b << 16) >> 24);
  r += ((int)(a << 8)  >> 24) * ((int)(b << 8)  >> 24);
  r += ((int)a >> 24)         * ((int)b >> 24);
  return r;
#endif
}

// f32 -> bf16 convert (n multiple of 1024)
__global__ __launch_bounds__(256) void cvt_bf16_k(const float* __restrict__ src,
                                                  ushort* __restrict__ dst) {
  const long i = ((long)blockIdx.x * 256 + threadIdx.x) * 4;
  float4 v = *(const float4*)(src + i);
  ushort4 o;
  o.x = f2bf(v.x); o.y = f2bf(v.y); o.z = f2bf(v.z); o.w = f2bf(v.w);
  *(ushort4*)(dst + i) = o;
}

// Transpose + bf16: dst(C x R) = src(R x C)^T. R,C multiples of 32.
__global__ __launch_bounds__(256) void tp_bf16_k(const float* __restrict__ src,
                                                 ushort* __restrict__ dst,
                                                 int R, int C) {
  __shared__ float tile[32][33];
  const int c0 = blockIdx.x * 32, r0 = blockIdx.y * 32;
  const int tx = threadIdx.x & 31, ty = threadIdx.x >> 5;  // ty 0..7
#pragma unroll
  for (int j = 0; j < 4; ++j)
    tile[ty + j * 8][tx] = src[(long)(r0 + ty + j * 8) * C + c0 + tx];
  __syncthreads();
#pragma unroll
  for (int j = 0; j < 4; ++j)
    dst[(long)(c0 + ty + j * 8) * R + r0 + tx] = f2bf(tile[tx][ty + j * 8]);
}

// Batched ushort transpose: dst[b](C x R) = src[b](R x C)^T, R=128, C=768.
__global__ __launch_bounds__(256) void emt_k(const ushort* __restrict__ src,
                                             ushort* __restrict__ dst) {
  __shared__ ushort tile[32][33];
  const int c0 = blockIdx.x * 32;   // col in src (0..767)
  const int r0 = blockIdx.y * 32;   // row in src (0..127)
  const int b = blockIdx.z;
  const ushort* s = src + (long)b * 98304;
  ushort* d = dst + (long)b * 98304;
  const int tx = threadIdx.x & 31, ty = threadIdx.x >> 5;
#pragma unroll
  for (int j = 0; j < 4; ++j)
    tile[ty + j * 8][tx] = s[(long)(r0 + ty + j * 8) * 768 + c0 + tx];
  __syncthreads();
#pragma unroll
  for (int j = 0; j < 4; ++j)
    d[(long)(c0 + ty + j * 8) * 128 + r0 + tx] = tile[tx][ty + j * 8];
}

// Whh (2,1024,256) f32 -> int8 dwords in lstm6 layout + per-row scale.
// lstm6 thread i reads w[k4*4+g] = Wq[((d*64 + k4)*4 + g)*256 + i]
// (coalesced in i). Source dword: (d, gate g, output i, k4).
__global__ __launch_bounds__(256) void pack_whh_i8_k(const float* __restrict__ Whh,
                                                     uint* __restrict__ Wq,
                                                     float* __restrict__ fscale) {
  const int wid = (blockIdx.x * 256 + threadIdx.x) >> 6;  // 0..2047 row (d,gi)
  const int lane = threadIdx.x & 63;                      // k4
  const int d = wid >> 10, gi = wid & 1023;
  const int g = gi >> 8, i = gi & 255;
  const float* row = Whh + ((long)d * 1024 + gi) * 256 + lane * 4;
  float v0 = row[0], v1 = row[1], v2 = row[2], v3 = row[3];
  float am = fmaxf(fmaxf(fabsf(v0), fabsf(v1)), fmaxf(fabsf(v2), fabsf(v3)));
#pragma unroll
  for (int off = 32; off > 0; off >>= 1) am = fmaxf(am, __shfl_xor(am, off, 64));
  am = fmaxf(am, 1e-12f);
  const float inv = 127.f / am;
  int q0 = __float2int_rn(v0 * inv), q1 = __float2int_rn(v1 * inv);
  int q2 = __float2int_rn(v2 * inv), q3 = __float2int_rn(v3 * inv);
  uint w = (uint)(q0 & 255) | ((uint)(q1 & 255) << 8) |
           ((uint)(q2 & 255) << 16) | ((uint)(q3 & 255) << 24);
  Wq[(long)(((d * 64 + lane) * 4 + g)) * 256 + i] = w;
  if (lane == 0) fscale[d * 1024 + gi] = am / 127.f;
}

// ---------------------------------------------------------------------------
// LSTM v6: one thread per output unit i, ALL 4 gates + full k=256 in-thread
// (256 int8 weight dwords register-resident). No gate-combine communication,
// no divergence, one barrier/step. 128 WGs = (dir, b); 256 threads.
// ---------------------------------------------------------------------------
__global__ __launch_bounds__(256, 1) void lstm6_k(
    const float* __restrict__ Xg,    // (2, 8192, 1024) x-part gate preacts
    const uint* __restrict__ Wq,     // lstm6-layout int8 dwords
    const float* __restrict__ fscale,// (2, 1024)
    ushort* __restrict__ out)        // (128, 64, 512) bf16
{
  const int bx = blockIdx.x;         // d*64 + b
  const int d = bx >> 6, b = bx & 63;
  const int i = threadIdx.x;         // output unit 0..255

  __shared__ uint hq[2][64];         // int8 h, double-buffered

  // whole 4-gate weight block for unit i in registers (256 VGPRs)
  uint w[256];
  {
    const uint* wb = Wq + (long)d * 65536 + i;
#pragma unroll
    for (int q = 0; q < 256; ++q) w[q] = wb[q * 256];
  }

  if (i < 64) hq[0][i] = 0u;

  const float* fs = fscale + d * 1024 + i;
  const float fsc0 = fs[0] * (1.f / 127.f);
  const float fsc1 = fs[256] * (1.f / 127.f);
  const float fsc2 = fs[512] * (1.f / 127.f);
  const float fsc3 = fs[768] * (1.f / 127.f);

  const float* Xd = Xg + (long)d * 8192 * 1024;

  float c = 0.f;
  float x0, x1, x2, x3;
  {
    const float* xr = Xd + ((long)((d ? 127 : 0) * 64 + b)) * 1024 + i;
    x0 = xr[0]; x1 = xr[256]; x2 = xr[512]; x3 = xr[768];
  }
  __syncthreads();

  int cur = 0;
  for (int step = 0; step < 128; ++step) {
    const int t = d ? 127 - step : step;

    // prefetch next-step x gates (coalesced; overlaps dot phase)
    float n0 = 0.f, n1 = 0.f, n2 = 0.f, n3 = 0.f;
    if (step + 1 < 128) {
      const float* xr = Xd + ((long)((d ? 126 - step : step + 1) * 64 + b)) * 1024 + i;
      n0 = xr[0]; n1 = xr[256]; n2 = xr[512]; n3 = xr[768];
    }

    int a0 = 0, a1 = 0, a2 = 0, a3 = 0;
    const uint4* h4p = (const uint4*)hq[cur];
#pragma unroll
    for (int k16 = 0; k16 < 16; ++k16) {
      uint4 h4 = h4p[k16];
      a0 = sdot4_(w[(k16 * 4 + 0) * 4 + 0], h4.x, a0);
      a1 = sdot4_(w[(k16 * 4 + 0) * 4 + 1], h4.x, a1);
      a2 = sdot4_(w[(k16 * 4 + 0) * 4 + 2], h4.x, a2);
      a3 = sdot4_(w[(k16 * 4 + 0) * 4 + 3], h4.x, a3);
      a0 = sdot4_(w[(k16 * 4 + 1) * 4 + 0], h4.y, a0);
      a1 = sdot4_(w[(k16 * 4 + 1) * 4 + 1], h4.y, a1);
      a2 = sdot4_(w[(k16 * 4 + 1) * 4 + 2], h4.y, a2);
      a3 = sdot4_(w[(k16 * 4 + 1) * 4 + 3], h4.y, a3);
      a0 = sdot4_(w[(k16 * 4 + 2) * 4 + 0], h4.z, a0);
      a1 = sdot4_(w[(k16 * 4 + 2) * 4 + 1], h4.z, a1);
      a2 = sdot4_(w[(k16 * 4 + 2) * 4 + 2], h4.z, a2);
      a3 = sdot4_(w[(k16 * 4 + 2) * 4 + 3], h4.z, a3);
      a0 = sdot4_(w[(k16 * 4 + 3) * 4 + 0], h4.w, a0);
      a1 = sdot4_(w[(k16 * 4 + 3) * 4 + 1], h4.w, a1);
      a2 = sdot4_(w[(k16 * 4 + 3) * 4 + 2], h4.w, a2);
      a3 = sdot4_(w[(k16 * 4 + 3) * 4 + 3], h4.w, a3);
    }

    const float p0 = x0 + (float)a0 * fsc0;
    const float p1 = x1 + (float)a1 * fsc1;
    const float p2 = x2 + (float)a2 * fsc2;
    const float p3 = x3 + (float)a3 * fsc3;
    const float ig = fast_sig(p0), fg = fast_sig(p1);
    const float gg = fast_tanh(p2), og = fast_sig(p3);
    c = fg * c + ig * gg;
    const float h = og * fast_tanh(c);
    out[((long)(t * 64 + b)) * 512 + (d << 8) + i] = f2bf(h);
    ((char*)hq[cur ^ 1])[i] = (char)__float2int_rn(h * 127.f);
    x0 = n0; x1 = n1; x2 = n2; x3 = n3;
    __syncthreads();
    cur ^= 1;
  }
}

// ---------------------------------------------------------------------------
// Edge attention softmax + window renorm. scores: (B, t, s)
// ---------------------------------------------------------------------------
__global__ __launch_bounds__(128) void edge_softmax_k(const float* __restrict__ scale,
                                                      float* __restrict__ scores) {
  const int bx = blockIdx.x;            // b*128 + t
  const int b = bx >> 7, t = bx & 127;
  const int s = threadIdx.x;
  __shared__ float red[128];
  const float v = scale[((long)(s * 64 + b)) * 128 + t];
  red[s] = v; __syncthreads();
  for (int off = 64; off > 0; off >>= 1) { if (s < off) red[s] = fmaxf(red[s], red[s + off]); __syncthreads(); }
  const float m = red[0]; __syncthreads();
  const float e = expf(v - m);
  red[s] = e; __syncthreads();
  for (int off = 64; off > 0; off >>= 1) { if (s < off) red[s] += red[s + off]; __syncthreads(); }
  const float esum = red[0]; __syncthreads();
  const float alpha = e / esum;
  const int dd = s - t;
  const bool inwin = (dd <= 10) && (dd >= -10);
  const float masked = alpha * (inwin ? 1.0f : 1e-10f);
  red[s] = masked; __syncthreads();
  for (int off = 64; off > 0; off >>= 1) { if (s < off) red[s] += red[s + off]; __syncthreads(); }
  const float msum = red[0];
  scores[(long)bx * 128 + s] = inwin ? (masked / msum) : 0.f;
}

// x b-major reorder (bf16 in, bf16 out)
__global__ __launch_bounds__(256) void xbuf_k(const ushort* __restrict__ featsbf,
                                              ushort* __restrict__ xbf) {
  const int n = blockIdx.x;
  const int b = n >> 7, t = n & 127;
  const int tid = threadIdx.x;
  const ushort* src = featsbf + (long)(t * 64 + b) * 512;
  ushort* dst = xbf + (long)n * 512;
  dst[tid] = src[tid];
  dst[tid + 256] = src[tid + 256];
}

// W_rel basis combination -> bf16 transposed (N=r*256+o rows, K=f cols)
__global__ __launch_bounds__(256) void wrel_k(const float* __restrict__ basis,
                                              const float* __restrict__ comp,
                                              ushort* __restrict__ wrel2t) {
  const int f = blockIdx.x;     // 0..511
  const int o = threadIdx.x;    // 0..255
  __shared__ float cs[240];
  if (o < 240) cs[o] = comp[o];
  __syncthreads();
  float acc[8];
#pragma unroll
  for (int r = 0; r < 8; ++r) acc[r] = 0.f;
  for (int bb = 0; bb < 30; ++bb) {
    const float v = basis[((long)bb * 512 + f) * 256 + o];
#pragma unroll
    for (int r = 0; r < 8; ++r) acc[r] = fmaf(cs[r * 30 + bb], v, acc[r]);
  }
#pragma unroll
  for (int r = 0; r < 8; ++r)
    wrel2t[((long)(r * 256 + o)) * 512 + f] = f2bf(acc[r]);
}

// RGCN message gather: h (f32) + hbf (bf16)
__global__ __launch_bounds__(256) void rgcn_gather_k(
    const float* __restrict__ xrel, const float* __restrict__ scores,
    const float* __restrict__ hroot, const int* __restrict__ spk,
    float* __restrict__ h, ushort* __restrict__ hbf)
{
  const int n = blockIdx.x;
  const int b = n >> 7, t = n & 127;
  const int o = threadIdx.x;
  const int lo = max(t - 10, 0), hi = min(t + 10, 127);
  const int cnt = hi - lo + 1;
  __shared__ int spks[21];
  __shared__ float wv[21];
  __shared__ int spkt_s;
  if (o < cnt) {
    spks[o] = spk[(lo + o) * 64 + b];
    wv[o] = scores[((long)(b * 128 + t)) * 128 + lo + o];
  }
  if (o == 0) spkt_s = spk[t * 64 + b];
  __syncthreads();
  const int spkt = spkt_s;
  float acc = hroot[(long)n * 256 + o];
  for (int q = 0; q < cnt; ++q) {
    const int s = lo + q;
    const int et = spkt * 4 + spks[q] * 2 + ((t < s) ? 0 : 1);
    acc = fmaf(xrel[(((long)(b * 128 + s)) * 8 + et) * 256 + o], wv[q], acc);
  }
  h[(long)n * 256 + o] = acc;
  hbf[(long)n * 256 + o] = f2bf(acc);
}

// GraphConv neighbor aggregation -> bf16
__global__ __launch_bounds__(256) void agg_k(const float* __restrict__ h,
                                             ushort* __restrict__ aggbf) {
  const int n = blockIdx.x;
  const int b = n >> 7, t = n & 127;
  const int o = threadIdx.x;
  const int lo = max(t - 10, 0), hi = min(t + 10, 127);
  float acc = 0.f;
  for (int s = lo; s <= hi; ++s) acc += h[((long)(b * 128 + s)) * 256 + o];
  aggbf[(long)n * 256 + o] = f2bf(acc);
}

// embf = concat(xbf, bf16(h2))
__global__ __launch_bounds__(256) void em_k(const ushort* __restrict__ xbf,
                                            const float* __restrict__ h2,
                                            ushort* __restrict__ embf) {
  const int n = blockIdx.x;
  const int tid = threadIdx.x;
  embf[(long)n * 768 + tid] = xbf[(long)n * 512 + tid];
  embf[(long)n * 768 + 256 + tid] = xbf[(long)n * 512 + 256 + tid];
  embf[(long)n * 768 + 512 + tid] = f2bf(h2[(long)n * 256 + tid]);
}

// Matching attention probs: logits f32 in, bf16 a out
__global__ __launch_bounds__(128) void match_softmax_k(const float* __restrict__ logits,
                                                       const float* __restrict__ umask,
                                                       ushort* __restrict__ abf) {
  const int bx = blockIdx.x;           // b*128 + t
  const int b = bx >> 7;
  const int s = threadIdx.x;
  __shared__ float red[128];
  const float* row = logits + (long)bx * 128;
  const float um = umask[b * 128 + s];
  const float v = tanhf(row[s] * um * um);
  red[s] = v; __syncthreads();
  for (int off = 64; off > 0; off >>= 1) { if (s < off) red[s] = fmaxf(red[s], red[s + off]); __syncthreads(); }
  const float m = red[0]; __syncthreads();
  const float e = expf(v - m);
  red[s] = e; __syncthreads();
  for (int off = 64; off > 0; off >>= 1) { if (s < off) red[s] += red[s + off]; __syncthreads(); }
  const float es = red[0]; __syncthreads();
  const float p = (e / es) * um;
  red[s] = p; __syncthreads();
  for (int off = 64; off > 0; off >>= 1) { if (s < off) red[s] += red[s + off]; __syncthreads(); }
  const float ps = red[0];
  abf[(long)bx * 128 + s] = f2bf(p / ps);
}

__global__ __launch_bounds__(256) void final_k(const float* __restrict__ hidden,
                                               const float* __restrict__ Ws,
                                               const float* __restrict__ bs,
                                               float* __restrict__ out) {
  __shared__ float wsl[256 * 6];
  const int tid = threadIdx.x;
#pragma unroll
  for (int j = 0; j < 6; ++j) wsl[tid * 6 + j] = Ws[tid * 6 + j];
  __syncthreads();
  const int wave = tid >> 6, lane = tid & 63;
  const int n = blockIdx.x * 4 + wave;
  const float4 hv = *(const float4*)&hidden[(long)n * 256 + lane * 4];
  const float hvv[4] = {hv.x, hv.y, hv.z, hv.w};
  float a[6];
#pragma unroll
  for (int c = 0; c < 6; ++c) a[c] = 0.f;
#pragma unroll
  for (int j = 0; j < 4; ++j)
#pragma unroll
    for (int c = 0; c < 6; ++c)
      a[c] = fmaf(hvv[j], wsl[(lane * 4 + j) * 6 + c], a[c]);
#pragma unroll
  for (int off = 32; off > 0; off >>= 1)
#pragma unroll
    for (int c = 0; c < 6; ++c)
      a[c] += __shfl_xor(a[c], off, 64);
  if (lane == 0) {
    float v[6], m = -1e30f;
#pragma unroll
    for (int c = 0; c < 6; ++c) { v[c] = a[c] + bs[c]; m = fmaxf(m, v[c]); }
    float sum = 0.f;
#pragma unroll
    for (int c = 0; c < 6; ++c) sum += expf(v[c] - m);
    const float lse = m + logf(sum);
#pragma unroll
    for (int c = 0; c < 6; ++c) out[(long)n * 6 + c] = v[c] - lse;
  }
}

// ---------------------------------------------------------------------------
// Orchestration
// ---------------------------------------------------------------------------
extern "C" void kernel_launch(void* const* d_in, const int* in_sizes, int n_in,
                              void* d_out, int out_size, void* d_ws, size_t ws_size,
                              hipStream_t stream) {
  const float* U        = (const float*)d_in[0];
  const float* umask    = (const float*)d_in[1];
  const float* Wih0     = (const float*)d_in[2];
  const float* Whh0     = (const float*)d_in[3];
  const float* b0       = (const float*)d_in[4];
  const float* Wih1     = (const float*)d_in[5];
  const float* Whh1     = (const float*)d_in[6];
  const float* b1       = (const float*)d_in[7];
  const float* W_scalar = (const float*)d_in[8];
  const float* basis    = (const float*)d_in[9];
  const float* comp     = (const float*)d_in[10];
  const float* W_root   = (const float*)d_in[11];
  const float* b_rgcn   = (const float*)d_in[12];
  const float* gc_W1    = (const float*)d_in[13];
  const float* gc_W2    = (const float*)d_in[14];
  const float* gc_b     = (const float*)d_in[15];
  const float* Wm       = (const float*)d_in[16];
  const float* bm       = (const float*)d_in[17];
  const float* Wl       = (const float*)d_in[18];
  const float* bl       = (const float*)d_in[19];
  const float* Wsw      = (const float*)d_in[20];
  const float* bsw      = (const float*)d_in[21];
  const int*   speakers = (const int*)d_in[22];

  float* ws = (float*)d_ws;
  // Regions (float offsets), reused across phases (lifetimes audited):
  float* gates   = ws + 0L;          // 16.78M f: gates0/1 -> xrel -> xtrbf
  float* feats   = ws + 16777216L;   //  4.19M f: wih0bf/wih1bf -> featsbf -> attbf
  float* xbuf    = ws + 20971520L;   //  4.19M f: ubf -> xbf -> emT
  float* feats0  = ws + 25165824L;   //  4.19M f: f0bf -> h/hbf/aggbf -> embf
  float* scaleb  = ws + 29360128L;   //  1.05M f: scale -> logits -> hidden(lo)
  float* scoresb = ws + 30408704L;   //  1.05M f: wscT -> edge scores -> abf -> hidden(hi)
  float* wrelr   = ws + 31457280L;   //  1.05M f: wrel2t bf16
  float* hroot   = ws + 32505856L;   //  2.10M f: hroot -> h2
  uint*  wq      = (uint*)(ws + 34603008L);   // 262,144 dwords
  float* fsc     = ws + 34865152L;            // 4,096
  float* wTr     = ws + 34869248L;            // 524,288 f (transposed bf16 weights)

  ushort* ubf    = (ushort*)xbuf;
  ushort* wih0bf = (ushort*)feats;               // [0..1.05M f)
  ushort* wih1bf = (ushort*)(feats + 1048576L);  // [1.05..1.57M f)
  ushort* featsbf= (ushort*)(feats + 2097152L);  // [2.1..4.19M f)
  ushort* f0bf   = (ushort*)feats0;              // [0..2.1M f)
  ushort* xbf    = (ushort*)xbuf;                // [0..2.1M f) (ubf dead)
  ushort* wrel2t = (ushort*)wrelr;
  ushort* wroott = (ushort*)wTr;                 // 131,072 us
  ushort* gcW1t  = wroott + 131072L;             //  65,536 us
  ushort* gcW2t  = gcW1t + 65536L;               //  65,536 us
  ushort* Wmt    = gcW2t + 65536L;               // 589,824 us
  ushort* Wlt    = Wmt + 589824L;                // 196,608 us
  ushort* wscT   = (ushort*)scoresb;             // 65,536 us (dead before edge_softmax)

  float*  hb      = feats0;                      // f32 [0..2.1M f)
  ushort* hbf     = (ushort*)(feats0 + 2097152L);
  ushort* aggbf   = (ushort*)(feats0 + 3145728L);
  ushort* embf    = (ushort*)feats0;             // 6.29M us [0..3.15M f)
  ushort* emT     = (ushort*)xbuf;               // 6.29M us [0..3.15M f) (xbf dead)
  ushort* xtrbf   = (ushort*)gates;              // 6.29M us (xrel dead)
  ushort* abf     = (ushort*)scoresb;            // 1.05M us (edge scores dead)
  ushort* attbf   = (ushort*)feats;              // 6.29M us [0..3.15M f) (featsbf dead)

  float*  xrel    = gates;
  float*  h2b     = hroot;
  float*  logitsb = scaleb;
  float*  hiddenb = scaleb;                      // 2.1M f spans scaleb+scoresb

  // --- weight prep ---
  pack_whh_i8_k<<<512, 256, 0, stream>>>(Whh0, wq, fsc);
  pack_whh_i8_k<<<512, 256, 0, stream>>>(Whh1, wq + 131072, fsc + 2048);
  cvt_bf16_k<<<8192, 256, 0, stream>>>(U, ubf);
  cvt_bf16_k<<<2048, 256, 0, stream>>>(Wih0, wih0bf);
  cvt_bf16_k<<<1024, 256, 0, stream>>>(Wih1, wih1bf);
  tp_bf16_k<<<dim3(8, 16), 256, 0, stream>>>(W_root, wroott, 512, 256);
  tp_bf16_k<<<dim3(8, 8), 256, 0, stream>>>(gc_W1, gcW1t, 256, 256);
  tp_bf16_k<<<dim3(8, 8), 256, 0, stream>>>(gc_W2, gcW2t, 256, 256);
  tp_bf16_k<<<dim3(24, 24), 256, 0, stream>>>(Wm, Wmt, 768, 768);
  tp_bf16_k<<<dim3(8, 24), 256, 0, stream>>>(Wl, Wlt, 768, 256);
  tp_bf16_k<<<dim3(4, 16), 256, 0, stream>>>(W_scalar, wscT, 512, 128);
  wrel_k<<<512, 256, 0, stream>>>(basis, comp, wrel2t);

  // --- layer 0 ---
  gemm_bf16_nt<true, false, false, false><<<dim3(8, 64, 2), 256, 0, stream>>>(
      ubf, wih0bf, b0, gates, 8192, 1024, 1024, 0L, 1048576L, 8388608L, 1024L);
  lstm6_k<<<128, 256, 0, stream>>>(gates, wq, fsc, f0bf);

  // --- layer 1 ---
  gemm_bf16_nt<true, false, false, false><<<dim3(8, 64, 2), 256, 0, stream>>>(
      f0bf, wih1bf, b1, gates, 8192, 1024, 512, 0L, 524288L, 8388608L, 1024L);
  lstm6_k<<<128, 256, 0, stream>>>(gates, wq + 131072, fsc + 2048, featsbf);

  // --- edge attention scores ---
  gemm_bf16_nt<false, false, false, false><<<dim3(1, 64, 1), 256, 0, stream>>>(
      featsbf, wscT, nullptr, scaleb, 8192, 128, 512, 0L, 0L, 0L, 0L);
  edge_softmax_k<<<8192, 128, 0, stream>>>(scaleb, scoresb);

  // --- node features (b-major) + RGCN ---
  xbuf_k<<<8192, 256, 0, stream>>>(featsbf, xbf);
  gemm_bf16_nt<true, false, false, false><<<dim3(2, 64, 1), 256, 0, stream>>>(
      xbf, wroott, b_rgcn, hroot, 8192, 256, 512, 0L, 0L, 0L, 0L);
  gemm_bf16_nt<false, false, false, false><<<dim3(16, 64, 1), 256, 0, stream>>>(
      xbf, wrel2t, nullptr, xrel, 8192, 2048, 512, 0L, 0L, 0L, 0L);
  rgcn_gather_k<<<8192, 256, 0, stream>>>(xrel, scoresb, hroot, speakers, hb, hbf);

  // --- GraphConv ---
  agg_k<<<8192, 256, 0, stream>>>(hb, aggbf);
  gemm_bf16_nt<true, false, false, false><<<dim3(2, 64, 1), 256, 0, stream>>>(
      hbf, gcW1t, gc_b, h2b, 8192, 256, 256, 0L, 0L, 0L, 0L);
  gemm_bf16_nt<false, true, false, false><<<dim3(2, 64, 1), 256, 0, stream>>>(
      aggbf, gcW2t, nullptr, h2b, 8192, 256, 256, 0L, 0L, 0L, 0L);

  // --- matching attention ---
  em_k<<<8192, 256, 0, stream>>>(xbf, h2b, embf);
  gemm_bf16_nt<true, false, false, true><<<dim3(6, 64, 1), 256, 0, stream>>>(
      embf, Wmt, bm, xtrbf, 8192, 768, 768, 0L, 0L, 0L, 0L);
  emt_k<<<dim3(24, 4, 64), 256, 0, stream>>>(embf, emT);
  gemm_bf16_nt<false, false, false, false><<<dim3(1, 1, 64), 256, 0, stream>>>(
      xtrbf, embf, nullptr, logitsb, 128, 128, 768, 98304L, 98304L, 16384L, 0L);
  match_softmax_k<<<8192, 128, 0, stream>>>(logitsb, umask, abf);
  gemm_bf16_nt<false, false, false, true><<<dim3(6, 1, 64), 256, 0, stream>>>(
      abf, emT, nullptr, attbf, 128, 768, 128, 16384L, 98304L, 98304L, 0L);

  // --- classifier ---
  gemm_bf16_nt<true, false, true, false><<<dim3(2, 64, 1), 256, 0, stream>>>(
      attbf, Wlt, bl, hiddenb, 8192, 256, 768, 0L, 0L, 0L, 0L);
  final_k<<<2048, 256, 0, stream>>>(hiddenb, Wsw, bsw, (float*)d_out);
}

// Round 9
// 664.882 us; speedup vs baseline: 1.2738x; 1.2738x over previous
//
#include <hip/hip_runtime.h>
#include <cstdint>

// Model dims (fixed): L=128, B=64, DM=1024, H=256, F=512, HID=256, MEM=768,
// N=B*L=8192, NC=6, R=8, NB=30, WIN=10

typedef __attribute__((ext_vector_type(8))) short bf16x8;
typedef __attribute__((ext_vector_type(4))) float f32x4;

// ---------------------------------------------------------------------------
// bf16 NT MFMA GEMM: C(MxN) = A(MxK)bf16 @ Bt(NxK)bf16^T (+bias)(+accum)
// C is f32, or bf16 when OUTBF. Batched via blockIdx.z (sA/sB/sC/sBias elem
// strides). 128x128x32 tile, 4 waves (2x2), 16x16x32 MFMA, 4x4 frags/wave.
// ---------------------------------------------------------------------------
template<bool HASBIAS, bool ACCUM, bool RELU, bool OUTBF>
__global__ __launch_bounds__(256) void gemm_bf16_nt(
    const ushort* __restrict__ A, const ushort* __restrict__ Bt,
    const float* __restrict__ bias, void* __restrict__ Cv,
    int M, int N, int K, long sA, long sB, long sC, long sBias)
{
  const int bz = blockIdx.z;
  A += (long)bz * sA;
  Bt += (long)bz * sB;
  if (HASBIAS) bias += (long)bz * sBias;
  float*  Cf = OUTBF ? nullptr : ((float*)Cv + (long)bz * sC);
  ushort* Cb = OUTBF ? ((ushort*)Cv + (long)bz * sC) : nullptr;

  const int bn = blockIdx.x * 128, bm = blockIdx.y * 128;

  __shared__ ushort As[128][40];   // +8 pad: benign 2-way bank aliasing
  __shared__ ushort Bs[128][40];

  const int tid = threadIdx.x;
  const int wave = tid >> 6, lane = tid & 63;
  const int wm = (wave >> 1) * 64, wn = (wave & 1) * 64;
  const int fr = lane & 15;
  const int fk = (lane >> 4) * 8;

  f32x4 acc[4][4];
#pragma unroll
  for (int i = 0; i < 4; ++i)
#pragma unroll
    for (int j = 0; j < 4; ++j) acc[i][j] = (f32x4){0.f, 0.f, 0.f, 0.f};

  const int sr = tid >> 1;
  const int sq = (tid & 1) * 16;

  for (int k0 = 0; k0 < K; k0 += 32) {
    const uint4* ga = (const uint4*)(A + (long)(bm + sr) * K + k0 + sq);
    uint4 av0 = ga[0], av1 = ga[1];
    const uint4* gb = (const uint4*)(Bt + (long)(bn + sr) * K + k0 + sq);
    uint4 bv0 = gb[0], bv1 = gb[1];
    *(uint4*)&As[sr][sq] = av0;
    *(uint4*)&As[sr][sq + 8] = av1;
    *(uint4*)&Bs[sr][sq] = bv0;
    *(uint4*)&Bs[sr][sq + 8] = bv1;
    __syncthreads();

    bf16x8 af[4], bfr[4];
#pragma unroll
    for (int f = 0; f < 4; ++f) {
      af[f]  = *(const bf16x8*)&As[wm + f * 16 + fr][fk];
      bfr[f] = *(const bf16x8*)&Bs[wn + f * 16 + fr][fk];
    }
#pragma unroll
    for (int mf = 0; mf < 4; ++mf)
#pragma unroll
      for (int nf = 0; nf < 4; ++nf)
        acc[mf][nf] = __builtin_amdgcn_mfma_f32_16x16x32_bf16(
            af[mf], bfr[nf], acc[mf][nf], 0, 0, 0);
    __syncthreads();
  }

  float bv[4];
#pragma unroll
  for (int nf = 0; nf < 4; ++nf)
    bv[nf] = HASBIAS ? bias[bn + wn + nf * 16 + fr] : 0.f;

  const int crow0 = (lane >> 4) * 4;
#pragma unroll
  for (int mf = 0; mf < 4; ++mf)
#pragma unroll
    for (int r = 0; r < 4; ++r) {
      const long roff = (long)(bm + wm + mf * 16 + crow0 + r) * N + bn + wn;
#pragma unroll
      for (int nf = 0; nf < 4; ++nf) {
        float v = acc[mf][nf][r] + bv[nf];
        if (OUTBF) {
          unsigned u = __float_as_uint(v);
          u += 0x7fffu + ((u >> 16) & 1u);
          Cb[roff + nf * 16 + fr] = (ushort)(u >> 16);
        } else {
          if (ACCUM) v += Cf[roff + nf * 16 + fr];
          if (RELU) v = fmaxf(v, 0.f);
          Cf[roff + nf * 16 + fr] = v;
        }
      }
    }
}

// ---------------------------------------------------------------------------
// helpers
// ---------------------------------------------------------------------------
__device__ __forceinline__ unsigned short f2bf(float f) {
  unsigned u = __float_as_uint(f);
  u += 0x7fffu + ((u >> 16) & 1u);
  return (unsigned short)(u >> 16);
}
__device__ __forceinline__ float bf2f(ushort v) {
  return __uint_as_float(((unsigned)v) << 16);
}
__device__ __forceinline__ float fast_sig(float x) {
  return __builtin_amdgcn_rcpf(1.f + __expf(-x));
}
__device__ __forceinline__ float fast_tanh(float x) {
  return 2.f * fast_sig(2.f * x) - 1.f;
}

__device__ __forceinline__ int sdot4_(uint a, uint b, int c) {
#if __has_builtin(__builtin_amdgcn_sdot4)
  return __builtin_amdgcn_sdot4((int)a, (int)b, c, false);
#else
  int r = c;
  r += ((int)(a << 24) >> 24) * ((int)(b << 24) >> 24);
  r += ((int)(a << 16) >> 24) * ((int)(b << 16) >> 24);
  r += ((int)(a << 8)  >> 24) * ((int)(b << 8)  >> 24);
  r += ((int)a >> 24)         * ((int)b >> 24);
  return r;
#endif
}

// f32 -> bf16 convert (n multiple of 1024)
__global__ __launch_bounds__(256) void cvt_bf16_k(const float* __restrict__ src,
                                                  ushort* __restrict__ dst) {
  const long i = ((long)blockIdx.x * 256 + threadIdx.x) * 4;
  float4 v = *(const float4*)(src + i);
  ushort4 o;
  o.x = f2bf(v.x); o.y = f2bf(v.y); o.z = f2bf(v.z); o.w = f2bf(v.w);
  *(ushort4*)(dst + i) = o;
}

// Transpose + bf16: dst(C x R) = src(R x C)^T. R,C multiples of 32.
__global__ __launch_bounds__(256) void tp_bf16_k(const float* __restrict__ src,
                                                 ushort* __restrict__ dst,
                                                 int R, int C) {
  __shared__ float tile[32][33];
  const int c0 = blockIdx.x * 32, r0 = blockIdx.y * 32;
  const int tx = threadIdx.x & 31, ty = threadIdx.x >> 5;  // ty 0..7
#pragma unroll
  for (int j = 0; j < 4; ++j)
    tile[ty + j * 8][tx] = src[(long)(r0 + ty + j * 8) * C + c0 + tx];
  __syncthreads();
#pragma unroll
  for (int j = 0; j < 4; ++j)
    dst[(long)(c0 + ty + j * 8) * R + r0 + tx] = f2bf(tile[tx][ty + j * 8]);
}

// Batched ushort transpose: dst[b](C x R) = src[b](R x C)^T, R=128, C=768.
__global__ __launch_bounds__(256) void emt_k(const ushort* __restrict__ src,
                                             ushort* __restrict__ dst) {
  __shared__ ushort tile[32][33];
  const int c0 = blockIdx.x * 32;
  const int r0 = blockIdx.y * 32;
  const int b = blockIdx.z;
  const ushort* s = src + (long)b * 98304;
  ushort* d = dst + (long)b * 98304;
  const int tx = threadIdx.x & 31, ty = threadIdx.x >> 5;
#pragma unroll
  for (int j = 0; j < 4; ++j)
    tile[ty + j * 8][tx] = s[(long)(r0 + ty + j * 8) * 768 + c0 + tx];
  __syncthreads();
#pragma unroll
  for (int j = 0; j < 4; ++j)
    d[(long)(c0 + ty + j * 8) * 128 + r0 + tx] = tile[tx][ty + j * 8];
}

// Whh (2,1024,256) f32 -> int8 [d][k4][gi] dwords + per-row scale [d][gi]
// (round-6 / lstm4 layout)
__global__ __launch_bounds__(256) void pack_whh_i8_k(const float* __restrict__ Whh,
                                                     uint* __restrict__ Wq,
                                                     float* __restrict__ fscale) {
  const int wid = (blockIdx.x * 256 + threadIdx.x) >> 6;  // 0..2047
  const int lane = threadIdx.x & 63;
  const int d = wid >> 10, gi = wid & 1023;
  const float* row = Whh + ((long)d * 1024 + gi) * 256 + lane * 4;
  float v0 = row[0], v1 = row[1], v2 = row[2], v3 = row[3];
  float am = fmaxf(fmaxf(fabsf(v0), fabsf(v1)), fmaxf(fabsf(v2), fabsf(v3)));
#pragma unroll
  for (int off = 32; off > 0; off >>= 1) am = fmaxf(am, __shfl_xor(am, off, 64));
  am = fmaxf(am, 1e-12f);
  const float inv = 127.f / am;
  int q0 = __float2int_rn(v0 * inv), q1 = __float2int_rn(v1 * inv);
  int q2 = __float2int_rn(v2 * inv), q3 = __float2int_rn(v3 * inv);
  uint w = (uint)(q0 & 255) | ((uint)(q1 & 255) << 8) |
           ((uint)(q2 & 255) << 16) | ((uint)(q3 & 255) << 24);
  Wq[((long)d * 64 + lane) * 1024 + gi] = w;
  if (lane == 0) fscale[d * 1024 + gi] = am / 127.f;
}

// ---------------------------------------------------------------------------
// LSTM v4 (round-6 proven): int8 weights streamed from L2, int8 h via LDS
// broadcast, sdot4; bf16 output. 128 WGs = (dir, b); 1024 thr = (gate, i).
// bmajor=0: out[(t*64+b)*512 + d*256 + i] ; bmajor=1: out[(b*128+t)*512 + ...]
// ---------------------------------------------------------------------------
__global__ __launch_bounds__(1024) void lstm4_k(
    const float* __restrict__ Xg,    // (2, 8192, 1024) x-part gate preacts
    const uint* __restrict__ Wq,     // (2, 64, 1024) int8-packed dwords
    const float* __restrict__ fscale,// (2, 1024)
    ushort* __restrict__ out,        // bf16
    int bmajor)
{
  const int bx = blockIdx.x;         // d*64 + b
  const int d = bx >> 6, b = bx & 63;
  const int tid = threadIdx.x;       // gi = g*256+i

  __shared__ uint hq[2][64];         // int8 h, double-buffered
  __shared__ float preactF[1024];

  uint w[64];
  const uint* wrow = Wq + (long)d * 65536 + tid;
#pragma unroll
  for (int k4 = 0; k4 < 64; ++k4) w[k4] = wrow[k4 * 1024];

  if (tid < 128) ((uint*)hq)[tid] = 0u;

  const float fsc = fscale[d * 1024 + tid] * (1.0f / 127.0f);
  const float* Xd = Xg + (long)d * 8192 * 1024;

  float c = 0.f;
  float x0 = 0.f, x1 = 0.f, x2 = 0.f, x3 = 0.f;
  if (tid < 256) {
    const float* xr = Xd + ((long)((d ? 127 : 0) * 64 + b)) * 1024;
    x0 = xr[tid]; x1 = xr[tid + 256]; x2 = xr[tid + 512]; x3 = xr[tid + 768];
  }
  __syncthreads();

  int cur = 0;
  for (int step = 0; step < 128; ++step) {
    const int t = d ? 127 - step : step;

    float n0 = 0.f, n1 = 0.f, n2 = 0.f, n3 = 0.f;
    if (tid < 256 && step + 1 < 128) {
      const float* xr = Xd + ((long)((d ? 126 - step : step + 1) * 64 + b)) * 1024;
      n0 = xr[tid]; n1 = xr[tid + 256]; n2 = xr[tid + 512]; n3 = xr[tid + 768];
    }

    int acc = 0;
    const uint4* hrow = (const uint4*)hq[cur];
#pragma unroll
    for (int k16 = 0; k16 < 16; ++k16) {
      uint4 h4 = hrow[k16];
      acc = sdot4_(w[k16 * 4 + 0], h4.x, acc);
      acc = sdot4_(w[k16 * 4 + 1], h4.y, acc);
      acc = sdot4_(w[k16 * 4 + 2], h4.z, acc);
      acc = sdot4_(w[k16 * 4 + 3], h4.w, acc);
    }
    preactF[tid] = (float)acc * fsc;
    __syncthreads();

    if (tid < 256) {
      float p0 = x0 + preactF[tid];
      float p1 = x1 + preactF[tid + 256];
      float p2 = x2 + preactF[tid + 512];
      float p3 = x3 + preactF[tid + 768];
      const float ig = fast_sig(p0), fg = fast_sig(p1);
      const float gg = fast_tanh(p2), og = fast_sig(p3);
      c = fg * c + ig * gg;
      const float h = og * fast_tanh(c);
      const long row = bmajor ? ((long)b * 128 + t) : ((long)t * 64 + b);
      out[row * 512 + (d << 8) + tid] = f2bf(h);
      ((char*)hq[cur ^ 1])[tid] = (char)__float2int_rn(h * 127.f);
      x0 = n0; x1 = n1; x2 = n2; x3 = n3;
    }
    __syncthreads();
    cur ^= 1;
  }
}

// ---------------------------------------------------------------------------
// Edge attention softmax + window renorm. scale rows are (b*128+s), cols t.
// scores: (B, t, s)
// ---------------------------------------------------------------------------
__global__ __launch_bounds__(128) void edge_softmax_k(const float* __restrict__ scale,
                                                      float* __restrict__ scores) {
  const int bx = blockIdx.x;            // b*128 + t
  const int b = bx >> 7, t = bx & 127;
  const int s = threadIdx.x;
  __shared__ float red[128];
  const float v = scale[((long)(b * 128 + s)) * 128 + t];
  red[s] = v; __syncthreads();
  for (int off = 64; off > 0; off >>= 1) { if (s < off) red[s] = fmaxf(red[s], red[s + off]); __syncthreads(); }
  const float m = red[0]; __syncthreads();
  const float e = expf(v - m);
  red[s] = e; __syncthreads();
  for (int off = 64; off > 0; off >>= 1) { if (s < off) red[s] += red[s + off]; __syncthreads(); }
  const float esum = red[0]; __syncthreads();
  const float alpha = e / esum;
  const int dd = s - t;
  const bool inwin = (dd <= 10) && (dd >= -10);
  const float masked = alpha * (inwin ? 1.0f : 1e-10f);
  red[s] = masked; __syncthreads();
  for (int off = 64; off > 0; off >>= 1) { if (s < off) red[s] += red[s + off]; __syncthreads(); }
  const float msum = red[0];
  scores[(long)bx * 128 + s] = inwin ? (masked / msum) : 0.f;
}

// W_rel basis combination -> bf16 transposed (N=r*256+o rows, K=f cols)
__global__ __launch_bounds__(256) void wrel_k(const float* __restrict__ basis,
                                              const float* __restrict__ comp,
                                              ushort* __restrict__ wrel2t) {
  const int f = blockIdx.x;     // 0..511
  const int o = threadIdx.x;    // 0..255
  __shared__ float cs[240];
  if (o < 240) cs[o] = comp[o];
  __syncthreads();
  float acc[8];
#pragma unroll
  for (int r = 0; r < 8; ++r) acc[r] = 0.f;
  for (int bb = 0; bb < 30; ++bb) {
    const float v = basis[((long)bb * 512 + f) * 256 + o];
#pragma unroll
    for (int r = 0; r < 8; ++r) acc[r] = fmaf(cs[r * 30 + bb], v, acc[r]);
  }
#pragma unroll
  for (int r = 0; r < 8; ++r)
    wrel2t[((long)(r * 256 + o)) * 512 + f] = f2bf(acc[r]);
}

// RGCN message gather: xrel is bf16; h (f32) + hbf (bf16) out
__global__ __launch_bounds__(256) void rgcn_gather_k(
    const ushort* __restrict__ xrel, const float* __restrict__ scores,
    const float* __restrict__ hroot, const int* __restrict__ spk,
    float* __restrict__ h, ushort* __restrict__ hbf)
{
  const int n = blockIdx.x;
  const int b = n >> 7, t = n & 127;
  const int o = threadIdx.x;
  const int lo = max(t - 10, 0), hi = min(t + 10, 127);
  const int cnt = hi - lo + 1;
  __shared__ int spks[21];
  __shared__ float wv[21];
  __shared__ int spkt_s;
  if (o < cnt) {
    spks[o] = spk[(lo + o) * 64 + b];
    wv[o] = scores[((long)(b * 128 + t)) * 128 + lo + o];
  }
  if (o == 0) spkt_s = spk[t * 64 + b];
  __syncthreads();
  const int spkt = spkt_s;
  float acc = hroot[(long)n * 256 + o];
  for (int q = 0; q < cnt; ++q) {
    const int s = lo + q;
    const int et = spkt * 4 + spks[q] * 2 + ((t < s) ? 0 : 1);
    acc = fmaf(bf2f(xrel[(((long)(b * 128 + s)) * 8 + et) * 256 + o]), wv[q], acc);
  }
  h[(long)n * 256 + o] = acc;
  hbf[(long)n * 256 + o] = f2bf(acc);
}

// GraphConv neighbor aggregation -> bf16
__global__ __launch_bounds__(256) void agg_k(const float* __restrict__ h,
                                             ushort* __restrict__ aggbf) {
  const int n = blockIdx.x;
  const int b = n >> 7, t = n & 127;
  const int o = threadIdx.x;
  const int lo = max(t - 10, 0), hi = min(t + 10, 127);
  float acc = 0.f;
  for (int s = lo; s <= hi; ++s) acc += h[((long)(b * 128 + s)) * 256 + o];
  aggbf[(long)n * 256 + o] = f2bf(acc);
}

// embf = concat(xbf, bf16(h2))
__global__ __launch_bounds__(256) void em_k(const ushort* __restrict__ xbf,
                                            const float* __restrict__ h2,
                                            ushort* __restrict__ embf) {
  const int n = blockIdx.x;
  const int tid = threadIdx.x;
  embf[(long)n * 768 + tid] = xbf[(long)n * 512 + tid];
  embf[(long)n * 768 + 256 + tid] = xbf[(long)n * 512 + 256 + tid];
  embf[(long)n * 768 + 512 + tid] = f2bf(h2[(long)n * 256 + tid]);
}

// Matching attention probs: logits f32 in, bf16 a out
__global__ __launch_bounds__(128) void match_softmax_k(const float* __restrict__ logits,
                                                       const float* __restrict__ umask,
                                                       ushort* __restrict__ abf) {
  const int bx = blockIdx.x;           // b*128 + t
  const int b = bx >> 7;
  const int s = threadIdx.x;
  __shared__ float red[128];
  const float* row = logits + (long)bx * 128;
  const float um = umask[b * 128 + s];
  const float v = tanhf(row[s] * um * um);
  red[s] = v; __syncthreads();
  for (int off = 64; off > 0; off >>= 1) { if (s < off) red[s] = fmaxf(red[s], red[s + off]); __syncthreads(); }
  const float m = red[0]; __syncthreads();
  const float e = expf(v - m);
  red[s] = e; __syncthreads();
  for (int off = 64; off > 0; off >>= 1) { if (s < off) red[s] += red[s + off]; __syncthreads(); }
  const float es = red[0]; __syncthreads();
  const float p = (e / es) * um;
  red[s] = p; __syncthreads();
  for (int off = 64; off > 0; off >>= 1) { if (s < off) red[s] += red[s + off]; __syncthreads(); }
  const float ps = red[0];
  abf[(long)bx * 128 + s] = f2bf(p / ps);
}

__global__ __launch_bounds__(256) void final_k(const float* __restrict__ hidden,
                                               const float* __restrict__ Ws,
                                               const float* __restrict__ bs,
                                               float* __restrict__ out) {
  __shared__ float wsl[256 * 6];
  const int tid = threadIdx.x;
#pragma unroll
  for (int j = 0; j < 6; ++j) wsl[tid * 6 + j] = Ws[tid * 6 + j];
  __syncthreads();
  const int wave = tid >> 6, lane = tid & 63;
  const int n = blockIdx.x * 4 + wave;
  const float4 hv = *(const float4*)&hidden[(long)n * 256 + lane * 4];
  const float hvv[4] = {hv.x, hv.y, hv.z, hv.w};
  float a[6];
#pragma unroll
  for (int c = 0; c < 6; ++c) a[c] = 0.f;
#pragma unroll
  for (int j = 0; j < 4; ++j)
#pragma unroll
    for (int c = 0; c < 6; ++c)
      a[c] = fmaf(hvv[j], wsl[(lane * 4 + j) * 6 + c], a[c]);
#pragma unroll
  for (int off = 32; off > 0; off >>= 1)
#pragma unroll
    for (int c = 0; c < 6; ++c)
      a[c] += __shfl_xor(a[c], off, 64);
  if (lane == 0) {
    float v[6], m = -1e30f;
#pragma unroll
    for (int c = 0; c < 6; ++c) { v[c] = a[c] + bs[c]; m = fmaxf(m, v[c]); }
    float sum = 0.f;
#pragma unroll
    for (int c = 0; c < 6; ++c) sum += expf(v[c] - m);
    const float lse = m + logf(sum);
#pragma unroll
    for (int c = 0; c < 6; ++c) out[(long)n * 6 + c] = v[c] - lse;
  }
}

// ---------------------------------------------------------------------------
// Orchestration
// ---------------------------------------------------------------------------
extern "C" void kernel_launch(void* const* d_in, const int* in_sizes, int n_in,
                              void* d_out, int out_size, void* d_ws, size_t ws_size,
                              hipStream_t stream) {
  const float* U        = (const float*)d_in[0];
  const float* umask    = (const float*)d_in[1];
  const float* Wih0     = (const float*)d_in[2];
  const float* Whh0     = (const float*)d_in[3];
  const float* b0       = (const float*)d_in[4];
  const float* Wih1     = (const float*)d_in[5];
  const float* Whh1     = (const float*)d_in[6];
  const float* b1       = (const float*)d_in[7];
  const float* W_scalar = (const float*)d_in[8];
  const float* basis    = (const float*)d_in[9];
  const float* comp     = (const float*)d_in[10];
  const float* W_root   = (const float*)d_in[11];
  const float* b_rgcn   = (const float*)d_in[12];
  const float* gc_W1    = (const float*)d_in[13];
  const float* gc_W2    = (const float*)d_in[14];
  const float* gc_b     = (const float*)d_in[15];
  const float* Wm       = (const float*)d_in[16];
  const float* bm       = (const float*)d_in[17];
  const float* Wl       = (const float*)d_in[18];
  const float* bl       = (const float*)d_in[19];
  const float* Wsw      = (const float*)d_in[20];
  const float* bsw      = (const float*)d_in[21];
  const int*   speakers = (const int*)d_in[22];

  float* ws = (float*)d_ws;
  // Regions (float offsets), reused across phases (lifetimes audited):
  float* gates   = ws + 0L;          // 16.78M f: gates0/1 -> xrelbf -> xtrbf
  float* feats   = ws + 16777216L;   //  4.19M f: wih0bf/wih1bf -> attbf
  float* xbuf    = ws + 20971520L;   //  4.19M f: ubf -> xbf (lstm L1 direct) -> emT
  float* feats0  = ws + 25165824L;   //  4.19M f: f0bf -> h/hbf/aggbf -> embf
  float* scaleb  = ws + 29360128L;   //  1.05M f: scale -> logits -> hidden(lo)
  float* scoresb = ws + 30408704L;   //  1.05M f: wscT -> edge scores -> abf -> hidden(hi)
  float* wrelr   = ws + 31457280L;   //  1.05M f: wrel2t bf16
  float* hroot   = ws + 32505856L;   //  2.10M f: hroot -> h2
  uint*  wq      = (uint*)(ws + 34603008L);   // 262,144 dwords
  float* fsc     = ws + 34865152L;            // 4,096
  float* wTr     = ws + 34869248L;            // 524,288 f (transposed bf16 weights)

  ushort* ubf    = (ushort*)xbuf;
  ushort* wih0bf = (ushort*)feats;               // [0..1.05M f)
  ushort* wih1bf = (ushort*)(feats + 1048576L);  // [1.05..1.57M f)
  ushort* f0bf   = (ushort*)feats0;              // [0..2.1M f)
  ushort* xbf    = (ushort*)xbuf;                // [0..2.1M f) (ubf dead after L0 gemm)
  ushort* wrel2t = (ushort*)wrelr;
  ushort* wroott = (ushort*)wTr;                 // 131,072 us
  ushort* gcW1t  = wroott + 131072L;             //  65,536 us
  ushort* gcW2t  = gcW1t + 65536L;               //  65,536 us
  ushort* Wmt    = gcW2t + 65536L;               // 589,824 us
  ushort* Wlt    = Wmt + 589824L;                // 196,608 us
  ushort* wscT   = (ushort*)scoresb;             // 65,536 us (dead before edge_softmax)

  float*  hb      = feats0;                      // f32 [0..2.1M f)
  ushort* hbf     = (ushort*)(feats0 + 2097152L);
  ushort* aggbf   = (ushort*)(feats0 + 3145728L);
  ushort* embf    = (ushort*)feats0;             // 6.29M us [0..3.15M f)
  ushort* emT     = (ushort*)xbuf;               // 6.29M us [0..3.15M f) (xbf dead)
  ushort* xrelbf  = (ushort*)gates;              // 16.78M us [0..8.39M f)
  ushort* xtrbf   = (ushort*)gates;              // 6.29M us (xrelbf dead)
  ushort* abf     = (ushort*)scoresb;            // 1.05M us (edge scores dead)
  ushort* attbf   = (ushort*)feats;              // 6.29M us [0..3.15M f)

  float*  h2b     = hroot;
  float*  logitsb = scaleb;
  float*  hiddenb = scaleb;                      // 2.1M f spans scaleb+scoresb

  // --- weight prep ---
  pack_whh_i8_k<<<512, 256, 0, stream>>>(Whh0, wq, fsc);
  pack_whh_i8_k<<<512, 256, 0, stream>>>(Whh1, wq + 131072, fsc + 2048);
  cvt_bf16_k<<<8192, 256, 0, stream>>>(U, ubf);
  cvt_bf16_k<<<2048, 256, 0, stream>>>(Wih0, wih0bf);
  cvt_bf16_k<<<1024, 256, 0, stream>>>(Wih1, wih1bf);
  tp_bf16_k<<<dim3(8, 16), 256, 0, stream>>>(W_root, wroott, 512, 256);
  tp_bf16_k<<<dim3(8, 8), 256, 0, stream>>>(gc_W1, gcW1t, 256, 256);
  tp_bf16_k<<<dim3(8, 8), 256, 0, stream>>>(gc_W2, gcW2t, 256, 256);
  tp_bf16_k<<<dim3(24, 24), 256, 0, stream>>>(Wm, Wmt, 768, 768);
  tp_bf16_k<<<dim3(8, 24), 256, 0, stream>>>(Wl, Wlt, 768, 256);
  tp_bf16_k<<<dim3(4, 16), 256, 0, stream>>>(W_scalar, wscT, 512, 128);
  wrel_k<<<512, 256, 0, stream>>>(basis, comp, wrel2t);

  // --- layer 0 ---
  gemm_bf16_nt<true, false, false, false><<<dim3(8, 64, 2), 256, 0, stream>>>(
      ubf, wih0bf, b0, gates, 8192, 1024, 1024, 0L, 1048576L, 8388608L, 1024L);
  lstm4_k<<<128, 1024, 0, stream>>>(gates, wq, fsc, f0bf, 0);

  // --- layer 1 (writes x directly in b-major) ---
  gemm_bf16_nt<true, false, false, false><<<dim3(8, 64, 2), 256, 0, stream>>>(
      f0bf, wih1bf, b1, gates, 8192, 1024, 512, 0L, 524288L, 8388608L, 1024L);
  lstm4_k<<<128, 1024, 0, stream>>>(gates, wq + 131072, fsc + 2048, xbf, 1);

  // --- edge attention scores (A = xbf, rows (b*128+s)) ---
  gemm_bf16_nt<false, false, false, false><<<dim3(1, 64, 1), 256, 0, stream>>>(
      xbf, wscT, nullptr, scaleb, 8192, 128, 512, 0L, 0L, 0L, 0L);
  edge_softmax_k<<<8192, 128, 0, stream>>>(scaleb, scoresb);

  // --- RGCN ---
  gemm_bf16_nt<true, false, false, false><<<dim3(2, 64, 1), 256, 0, stream>>>(
      xbf, wroott, b_rgcn, hroot, 8192, 256, 512, 0L, 0L, 0L, 0L);
  gemm_bf16_nt<false, false, false, true><<<dim3(16, 64, 1), 256, 0, stream>>>(
      xbf, wrel2t, nullptr, xrelbf, 8192, 2048, 512, 0L, 0L, 0L, 0L);
  rgcn_gather_k<<<8192, 256, 0, stream>>>(xrelbf, scoresb, hroot, speakers, hb, hbf);

  // --- GraphConv ---
  agg_k<<<8192, 256, 0, stream>>>(hb, aggbf);
  gemm_bf16_nt<true, false, false, false><<<dim3(2, 64, 1), 256, 0, stream>>>(
      hbf, gcW1t, gc_b, h2b, 8192, 256, 256, 0L, 0L, 0L, 0L);
  gemm_bf16_nt<false, true, false, false><<<dim3(2, 64, 1), 256, 0, stream>>>(
      aggbf, gcW2t, nullptr, h2b, 8192, 256, 256, 0L, 0L, 0L, 0L);

  // --- matching attention ---
  em_k<<<8192, 256, 0, stream>>>(xbf, h2b, embf);
  gemm_bf16_nt<true, false, false, true><<<dim3(6, 64, 1), 256, 0, stream>>>(
      embf, Wmt, bm, xtrbf, 8192, 768, 768, 0L, 0L, 0L, 0L);
  emt_k<<<dim3(24, 4, 64), 256, 0, stream>>>(embf, emT);
  gemm_bf16_nt<false, false, false, false><<<dim3(1, 1, 64), 256, 0, stream>>>(
      xtrbf, embf, nullptr, logitsb, 128, 128, 768, 98304L, 98304L, 16384L, 0L);
  match_softmax_k<<<8192, 128, 0, stream>>>(logitsb, umask, abf);
  gemm_bf16_nt<false, false, false, true><<<dim3(6, 1, 64), 256, 0, stream>>>(
      abf, emT, nullptr, attbf, 128, 768, 128, 16384L, 98304L, 98304L, 0L);

  // --- classifier ---
  gemm_bf16_nt<true, false, true, false><<<dim3(2, 64, 1), 256, 0, stream>>>(
      attbf, Wlt, bl, hiddenb, 8192, 256, 768, 0L, 0L, 0L, 0L);
  final_k<<<2048, 256, 0, stream>>>(hiddenb, Wsw, bsw, (float*)d_out);
}

// Round 10
// 646.979 us; speedup vs baseline: 1.3091x; 1.0277x over previous
//
#include <hip/hip_runtime.h>
#include <cstdint>

// Model dims (fixed): L=128, B=64, DM=1024, H=256, F=512, HID=256, MEM=768,
// N=B*L=8192, NC=6, R=8, NB=30, WIN=10

typedef __attribute__((ext_vector_type(8))) short bf16x8;
typedef __attribute__((ext_vector_type(4))) float f32x4;

__device__ __forceinline__ void gload_lds16(const void* g, void* l) {
  __builtin_amdgcn_global_load_lds(
      (const __attribute__((address_space(1))) void*)g,
      (__attribute__((address_space(3))) void*)l, 16, 0, 0);
}

// ---------------------------------------------------------------------------
// bf16 NT MFMA GEMM: C(MxN) = A(MxK)bf16 @ Bt(NxK)bf16^T (+bias)(+accum)
// C is f32, or bf16 when OUTBF. Batched via blockIdx.z. 128x128x32 tile,
// 4 waves (2x2), 16x16x32 MFMA, 4x4 frags/wave.
// Staging via global_load_lds width=16 (linear LDS, wave-uniform base).
// ---------------------------------------------------------------------------
template<bool HASBIAS, bool ACCUM, bool RELU, bool OUTBF>
__global__ __launch_bounds__(256) void gemm_bf16_nt(
    const ushort* __restrict__ A, const ushort* __restrict__ Bt,
    const float* __restrict__ bias, void* __restrict__ Cv,
    int M, int N, int K, long sA, long sB, long sC, long sBias)
{
  const int bz = blockIdx.z;
  A += (long)bz * sA;
  Bt += (long)bz * sB;
  if (HASBIAS) bias += (long)bz * sBias;
  float*  Cf = OUTBF ? nullptr : ((float*)Cv + (long)bz * sC);
  ushort* Cb = OUTBF ? ((ushort*)Cv + (long)bz * sC) : nullptr;

  const int bn = blockIdx.x * 128, bm = blockIdx.y * 128;

  __shared__ ushort As[128][32];   // linear (global_load_lds dest)
  __shared__ ushort Bs[128][32];

  const int tid = threadIdx.x;
  const int wave = tid >> 6, lane = tid & 63;
  const int wm = (wave >> 1) * 64, wn = (wave & 1) * 64;
  const int fr = lane & 15;
  const int fk = (lane >> 4) * 8;

  f32x4 acc[4][4];
#pragma unroll
  for (int i = 0; i < 4; ++i)
#pragma unroll
    for (int j = 0; j < 4; ++j) acc[i][j] = (f32x4){0.f, 0.f, 0.f, 0.f};

  // staging chunks: f = (wave*2+inst)*64 + lane, chunk=16B; row=f>>2, col=(f&3)*8
  const int f0 = wave * 2 * 64 + lane;
  const int f1 = f0 + 64;
  const int r0 = f0 >> 2, c0 = (f0 & 3) * 8;
  const int r1 = f1 >> 2, c1 = (f1 & 3) * 8;
  ushort* As0 = (ushort*)As + wave * 2 * 512;
  ushort* As1 = As0 + 512;
  ushort* Bs0 = (ushort*)Bs + wave * 2 * 512;
  ushort* Bs1 = Bs0 + 512;

  for (int k0 = 0; k0 < K; k0 += 32) {
    gload_lds16(A + (long)(bm + r0) * K + k0 + c0, As0);
    gload_lds16(A + (long)(bm + r1) * K + k0 + c1, As1);
    gload_lds16(Bt + (long)(bn + r0) * K + k0 + c0, Bs0);
    gload_lds16(Bt + (long)(bn + r1) * K + k0 + c1, Bs1);
    __syncthreads();

    bf16x8 af[4], bfr[4];
#pragma unroll
    for (int f = 0; f < 4; ++f) {
      af[f]  = *(const bf16x8*)&As[wm + f * 16 + fr][fk];
      bfr[f] = *(const bf16x8*)&Bs[wn + f * 16 + fr][fk];
    }
#pragma unroll
    for (int mf = 0; mf < 4; ++mf)
#pragma unroll
      for (int nf = 0; nf < 4; ++nf)
        acc[mf][nf] = __builtin_amdgcn_mfma_f32_16x16x32_bf16(
            af[mf], bfr[nf], acc[mf][nf], 0, 0, 0);
    __syncthreads();
  }

  float bv[4];
#pragma unroll
  for (int nf = 0; nf < 4; ++nf)
    bv[nf] = HASBIAS ? bias[bn + wn + nf * 16 + fr] : 0.f;

  const int crow0 = (lane >> 4) * 4;
#pragma unroll
  for (int mf = 0; mf < 4; ++mf)
#pragma unroll
    for (int r = 0; r < 4; ++r) {
      const long roff = (long)(bm + wm + mf * 16 + crow0 + r) * N + bn + wn;
#pragma unroll
      for (int nf = 0; nf < 4; ++nf) {
        float v = acc[mf][nf][r] + bv[nf];
        if (OUTBF) {
          unsigned u = __float_as_uint(v);
          u += 0x7fffu + ((u >> 16) & 1u);
          Cb[roff + nf * 16 + fr] = (ushort)(u >> 16);
        } else {
          if (ACCUM) v += Cf[roff + nf * 16 + fr];
          if (RELU) v = fmaxf(v, 0.f);
          Cf[roff + nf * 16 + fr] = v;
        }
      }
    }
}

// ---------------------------------------------------------------------------
// helpers
// ---------------------------------------------------------------------------
__device__ __forceinline__ unsigned short f2bf(float f) {
  unsigned u = __float_as_uint(f);
  u += 0x7fffu + ((u >> 16) & 1u);
  return (unsigned short)(u >> 16);
}
__device__ __forceinline__ float bf2f(ushort v) {
  return __uint_as_float(((unsigned)v) << 16);
}
__device__ __forceinline__ float fast_sig(float x) {
  return __builtin_amdgcn_rcpf(1.f + __expf(-x));
}
__device__ __forceinline__ float fast_tanh(float x) {
  return 2.f * fast_sig(2.f * x) - 1.f;
}

__device__ __forceinline__ int sdot4_(uint a, uint b, int c) {
#if __has_builtin(__builtin_amdgcn_sdot4)
  return __builtin_amdgcn_sdot4((int)a, (int)b, c, false);
#else
  int r = c;
  r += ((int)(a << 24) >> 24) * ((int)(b << 24) >> 24);
  r += ((int)(a << 16) >> 24) * ((int)(b << 16) >> 24);
  r += ((int)(a << 8)  >> 24) * ((int)(b << 8)  >> 24);
  r += ((int)a >> 24)         * ((int)b >> 24);
  return r;
#endif
}

// f32 -> bf16 convert (n multiple of 1024)
__global__ __launch_bounds__(256) void cvt_bf16_k(const float* __restrict__ src,
                                                  ushort* __restrict__ dst) {
  const long i = ((long)blockIdx.x * 256 + threadIdx.x) * 4;
  float4 v = *(const float4*)(src + i);
  ushort4 o;
  o.x = f2bf(v.x); o.y = f2bf(v.y); o.z = f2bf(v.z); o.w = f2bf(v.w);
  *(ushort4*)(dst + i) = o;
}

// Transpose + bf16: dst(C x R) = src(R x C)^T. R,C multiples of 32.
__global__ __launch_bounds__(256) void tp_bf16_k(const float* __restrict__ src,
                                                 ushort* __restrict__ dst,
                                                 int R, int C) {
  __shared__ float tile[32][33];
  const int c0 = blockIdx.x * 32, r0 = blockIdx.y * 32;
  const int tx = threadIdx.x & 31, ty = threadIdx.x >> 5;  // ty 0..7
#pragma unroll
  for (int j = 0; j < 4; ++j)
    tile[ty + j * 8][tx] = src[(long)(r0 + ty + j * 8) * C + c0 + tx];
  __syncthreads();
#pragma unroll
  for (int j = 0; j < 4; ++j)
    dst[(long)(c0 + ty + j * 8) * R + r0 + tx] = f2bf(tile[tx][ty + j * 8]);
}

// Batched ushort transpose: dst[b](C x R) = src[b](R x C)^T, R=128, C=768.
__global__ __launch_bounds__(256) void emt_k(const ushort* __restrict__ src,
                                             ushort* __restrict__ dst) {
  __shared__ ushort tile[32][33];
  const int c0 = blockIdx.x * 32;
  const int r0 = blockIdx.y * 32;
  const int b = blockIdx.z;
  const ushort* s = src + (long)b * 98304;
  ushort* d = dst + (long)b * 98304;
  const int tx = threadIdx.x & 31, ty = threadIdx.x >> 5;
#pragma unroll
  for (int j = 0; j < 4; ++j)
    tile[ty + j * 8][tx] = s[(long)(r0 + ty + j * 8) * 768 + c0 + tx];
  __syncthreads();
#pragma unroll
  for (int j = 0; j < 4; ++j)
    d[(long)(c0 + ty + j * 8) * 128 + r0 + tx] = tile[tx][ty + j * 8];
}

// Whh (2,1024,256) f32 -> int8 [d][k4][gi] dwords + per-row scale [d][gi]
__global__ __launch_bounds__(256) void pack_whh_i8_k(const float* __restrict__ Whh,
                                                     uint* __restrict__ Wq,
                                                     float* __restrict__ fscale) {
  const int wid = (blockIdx.x * 256 + threadIdx.x) >> 6;  // 0..2047
  const int lane = threadIdx.x & 63;
  const int d = wid >> 10, gi = wid & 1023;
  const float* row = Whh + ((long)d * 1024 + gi) * 256 + lane * 4;
  float v0 = row[0], v1 = row[1], v2 = row[2], v3 = row[3];
  float am = fmaxf(fmaxf(fabsf(v0), fabsf(v1)), fmaxf(fabsf(v2), fabsf(v3)));
#pragma unroll
  for (int off = 32; off > 0; off >>= 1) am = fmaxf(am, __shfl_xor(am, off, 64));
  am = fmaxf(am, 1e-12f);
  const float inv = 127.f / am;
  int q0 = __float2int_rn(v0 * inv), q1 = __float2int_rn(v1 * inv);
  int q2 = __float2int_rn(v2 * inv), q3 = __float2int_rn(v3 * inv);
  uint w = (uint)(q0 & 255) | ((uint)(q1 & 255) << 8) |
           ((uint)(q2 & 255) << 16) | ((uint)(q3 & 255) << 24);
  Wq[((long)d * 64 + lane) * 1024 + gi] = w;
  if (lane == 0) fscale[d * 1024 + gi] = am / 127.f;
}

// ---------------------------------------------------------------------------
// LSTM v4 (proven): int8 weights streamed from L2, int8 h via LDS broadcast,
// sdot4; bf16 output. 128 WGs = (dir, b); 1024 thr = (gate, i).
// ---------------------------------------------------------------------------
__global__ __launch_bounds__(1024) void lstm4_k(
    const float* __restrict__ Xg,    // (2, 8192, 1024) x-part gate preacts
    const uint* __restrict__ Wq,     // (2, 64, 1024) int8-packed dwords
    const float* __restrict__ fscale,// (2, 1024)
    ushort* __restrict__ out,        // bf16
    int bmajor)
{
  const int bx = blockIdx.x;         // d*64 + b
  const int d = bx >> 6, b = bx & 63;
  const int tid = threadIdx.x;       // gi = g*256+i

  __shared__ uint hq[2][64];         // int8 h, double-buffered
  __shared__ float preactF[1024];

  uint w[64];
  const uint* wrow = Wq + (long)d * 65536 + tid;
#pragma unroll
  for (int k4 = 0; k4 < 64; ++k4) w[k4] = wrow[k4 * 1024];

  if (tid < 128) ((uint*)hq)[tid] = 0u;

  const float fsc = fscale[d * 1024 + tid] * (1.0f / 127.0f);
  const float* Xd = Xg + (long)d * 8192 * 1024;

  float c = 0.f;
  float x0 = 0.f, x1 = 0.f, x2 = 0.f, x3 = 0.f;
  if (tid < 256) {
    const float* xr = Xd + ((long)((d ? 127 : 0) * 64 + b)) * 1024;
    x0 = xr[tid]; x1 = xr[tid + 256]; x2 = xr[tid + 512]; x3 = xr[tid + 768];
  }
  __syncthreads();

  int cur = 0;
  for (int step = 0; step < 128; ++step) {
    const int t = d ? 127 - step : step;

    float n0 = 0.f, n1 = 0.f, n2 = 0.f, n3 = 0.f;
    if (tid < 256 && step + 1 < 128) {
      const float* xr = Xd + ((long)((d ? 126 - step : step + 1) * 64 + b)) * 1024;
      n0 = xr[tid]; n1 = xr[tid + 256]; n2 = xr[tid + 512]; n3 = xr[tid + 768];
    }

    int acc = 0;
    const uint4* hrow = (const uint4*)hq[cur];
#pragma unroll
    for (int k16 = 0; k16 < 16; ++k16) {
      uint4 h4 = hrow[k16];
      acc = sdot4_(w[k16 * 4 + 0], h4.x, acc);
      acc = sdot4_(w[k16 * 4 + 1], h4.y, acc);
      acc = sdot4_(w[k16 * 4 + 2], h4.z, acc);
      acc = sdot4_(w[k16 * 4 + 3], h4.w, acc);
    }
    preactF[tid] = (float)acc * fsc;
    __syncthreads();

    if (tid < 256) {
      float p0 = x0 + preactF[tid];
      float p1 = x1 + preactF[tid + 256];
      float p2 = x2 + preactF[tid + 512];
      float p3 = x3 + preactF[tid + 768];
      const float ig = fast_sig(p0), fg = fast_sig(p1);
      const float gg = fast_tanh(p2), og = fast_sig(p3);
      c = fg * c + ig * gg;
      const float h = og * fast_tanh(c);
      const long row = bmajor ? ((long)b * 128 + t) : ((long)t * 64 + b);
      out[row * 512 + (d << 8) + tid] = f2bf(h);
      ((char*)hq[cur ^ 1])[tid] = (char)__float2int_rn(h * 127.f);
      x0 = n0; x1 = n1; x2 = n2; x3 = n3;
    }
    __syncthreads();
    cur ^= 1;
  }
}

// ---------------------------------------------------------------------------
// Edge attention softmax + window renorm. scale rows are (b*128+s), cols t.
// scores: (B, t, s)
// ---------------------------------------------------------------------------
__global__ __launch_bounds__(128) void edge_softmax_k(const float* __restrict__ scale,
                                                      float* __restrict__ scores) {
  const int bx = blockIdx.x;            // b*128 + t
  const int b = bx >> 7, t = bx & 127;
  const int s = threadIdx.x;
  __shared__ float red[128];
  const float v = scale[((long)(b * 128 + s)) * 128 + t];
  red[s] = v; __syncthreads();
  for (int off = 64; off > 0; off >>= 1) { if (s < off) red[s] = fmaxf(red[s], red[s + off]); __syncthreads(); }
  const float m = red[0]; __syncthreads();
  const float e = expf(v - m);
  red[s] = e; __syncthreads();
  for (int off = 64; off > 0; off >>= 1) { if (s < off) red[s] += red[s + off]; __syncthreads(); }
  const float esum = red[0]; __syncthreads();
  const float alpha = e / esum;
  const int dd = s - t;
  const bool inwin = (dd <= 10) && (dd >= -10);
  const float masked = alpha * (inwin ? 1.0f : 1e-10f);
  red[s] = masked; __syncthreads();
  for (int off = 64; off > 0; off >>= 1) { if (s < off) red[s] += red[s + off]; __syncthreads(); }
  const float msum = red[0];
  scores[(long)bx * 128 + s] = inwin ? (masked / msum) : 0.f;
}

// W_rel basis combination -> bf16 transposed (N=r*256+o rows, K=f cols)
__global__ __launch_bounds__(256) void wrel_k(const float* __restrict__ basis,
                                              const float* __restrict__ comp,
                                              ushort* __restrict__ wrel2t) {
  const int f = blockIdx.x;     // 0..511
  const int o = threadIdx.x;    // 0..255
  __shared__ float cs[240];
  if (o < 240) cs[o] = comp[o];
  __syncthreads();
  float acc[8];
#pragma unroll
  for (int r = 0; r < 8; ++r) acc[r] = 0.f;
  for (int bb = 0; bb < 30; ++bb) {
    const float v = basis[((long)bb * 512 + f) * 256 + o];
#pragma unroll
    for (int r = 0; r < 8; ++r) acc[r] = fmaf(cs[r * 30 + bb], v, acc[r]);
  }
#pragma unroll
  for (int r = 0; r < 8; ++r)
    wrel2t[((long)(r * 256 + o)) * 512 + f] = f2bf(acc[r]);
}

// RGCN message gather: xrel is bf16; h (f32) + hbf (bf16) out
__global__ __launch_bounds__(256) void rgcn_gather_k(
    const ushort* __restrict__ xrel, const float* __restrict__ scores,
    const float* __restrict__ hroot, const int* __restrict__ spk,
    float* __restrict__ h, ushort* __restrict__ hbf)
{
  const int n = blockIdx.x;
  const int b = n >> 7, t = n & 127;
  const int o = threadIdx.x;
  const int lo = max(t - 10, 0), hi = min(t + 10, 127);
  const int cnt = hi - lo + 1;
  __shared__ int spks[21];
  __shared__ float wv[21];
  __shared__ int spkt_s;
  if (o < cnt) {
    spks[o] = spk[(lo + o) * 64 + b];
    wv[o] = scores[((long)(b * 128 + t)) * 128 + lo + o];
  }
  if (o == 0) spkt_s = spk[t * 64 + b];
  __syncthreads();
  const int spkt = spkt_s;
  float acc = hroot[(long)n * 256 + o];
  for (int q = 0; q < cnt; ++q) {
    const int s = lo + q;
    const int et = spkt * 4 + spks[q] * 2 + ((t < s) ? 0 : 1);
    acc = fmaf(bf2f(xrel[(((long)(b * 128 + s)) * 8 + et) * 256 + o]), wv[q], acc);
  }
  h[(long)n * 256 + o] = acc;
  hbf[(long)n * 256 + o] = f2bf(acc);
}

// GraphConv neighbor aggregation -> bf16
__global__ __launch_bounds__(256) void agg_k(const float* __restrict__ h,
                                             ushort* __restrict__ aggbf) {
  const int n = blockIdx.x;
  const int b = n >> 7, t = n & 127;
  const int o = threadIdx.x;
  const int lo = max(t - 10, 0), hi = min(t + 10, 127);
  float acc = 0.f;
  for (int s = lo; s <= hi; ++s) acc += h[((long)(b * 128 + s)) * 256 + o];
  aggbf[(long)n * 256 + o] = f2bf(acc);
}

// embf = concat(xbf, bf16(h2))
__global__ __launch_bounds__(256) void em_k(const ushort* __restrict__ xbf,
                                            const float* __restrict__ h2,
                                            ushort* __restrict__ embf) {
  const int n = blockIdx.x;
  const int tid = threadIdx.x;
  embf[(long)n * 768 + tid] = xbf[(long)n * 512 + tid];
  embf[(long)n * 768 + 256 + tid] = xbf[(long)n * 512 + 256 + tid];
  embf[(long)n * 768 + 512 + tid] = f2bf(h2[(long)n * 256 + tid]);
}

// Matching attention probs: logits f32 in, bf16 a out
__global__ __launch_bounds__(128) void match_softmax_k(const float* __restrict__ logits,
                                                       const float* __restrict__ umask,
                                                       ushort* __restrict__ abf) {
  const int bx = blockIdx.x;           // b*128 + t
  const int b = bx >> 7;
  const int s = threadIdx.x;
  __shared__ float red[128];
  const float* row = logits + (long)bx * 128;
  const float um = umask[b * 128 + s];
  const float v = tanhf(row[s] * um * um);
  red[s] = v; __syncthreads();
  for (int off = 64; off > 0; off >>= 1) { if (s < off) red[s] = fmaxf(red[s], red[s + off]); __syncthreads(); }
  const float m = red[0]; __syncthreads();
  const float e = expf(v - m);
  red[s] = e; __syncthreads();
  for (int off = 64; off > 0; off >>= 1) { if (s < off) red[s] += red[s + off]; __syncthreads(); }
  const float es = red[0]; __syncthreads();
  const float p = (e / es) * um;
  red[s] = p; __syncthreads();
  for (int off = 64; off > 0; off >>= 1) { if (s < off) red[s] += red[s + off]; __syncthreads(); }
  const float ps = red[0];
  abf[(long)bx * 128 + s] = f2bf(p / ps);
}

__global__ __launch_bounds__(256) void final_k(const float* __restrict__ hidden,
                                               const float* __restrict__ Ws,
                                               const float* __restrict__ bs,
                                               float* __restrict__ out) {
  __shared__ float wsl[256 * 6];
  const int tid = threadIdx.x;
#pragma unroll
  for (int j = 0; j < 6; ++j) wsl[tid * 6 + j] = Ws[tid * 6 + j];
  __syncthreads();
  const int wave = tid >> 6, lane = tid & 63;
  const int n = blockIdx.x * 4 + wave;
  const float4 hv = *(const float4*)&hidden[(long)n * 256 + lane * 4];
  const float hvv[4] = {hv.x, hv.y, hv.z, hv.w};
  float a[6];
#pragma unroll
  for (int c = 0; c < 6; ++c) a[c] = 0.f;
#pragma unroll
  for (int j = 0; j < 4; ++j)
#pragma unroll
    for (int c = 0; c < 6; ++c)
      a[c] = fmaf(hvv[j], wsl[(lane * 4 + j) * 6 + c], a[c]);
#pragma unroll
  for (int off = 32; off > 0; off >>= 1)
#pragma unroll
    for (int c = 0; c < 6; ++c)
      a[c] += __shfl_xor(a[c], off, 64);
  if (lane == 0) {
    float v[6], m = -1e30f;
#pragma unroll
    for (int c = 0; c < 6; ++c) { v[c] = a[c] + bs[c]; m = fmaxf(m, v[c]); }
    float sum = 0.f;
#pragma unroll
    for (int c = 0; c < 6; ++c) sum += expf(v[c] - m);
    const float lse = m + logf(sum);
#pragma unroll
    for (int c = 0; c < 6; ++c) out[(long)n * 6 + c] = v[c] - lse;
  }
}

// ---------------------------------------------------------------------------
// Orchestration
// ---------------------------------------------------------------------------
extern "C" void kernel_launch(void* const* d_in, const int* in_sizes, int n_in,
                              void* d_out, int out_size, void* d_ws, size_t ws_size,
                              hipStream_t stream) {
  const float* U        = (const float*)d_in[0];
  const float* umask    = (const float*)d_in[1];
  const float* Wih0     = (const float*)d_in[2];
  const float* Whh0     = (const float*)d_in[3];
  const float* b0       = (const float*)d_in[4];
  const float* Wih1     = (const float*)d_in[5];
  const float* Whh1     = (const float*)d_in[6];
  const float* b1       = (const float*)d_in[7];
  const float* W_scalar = (const float*)d_in[8];
  const float* basis    = (const float*)d_in[9];
  const float* comp     = (const float*)d_in[10];
  const float* W_root   = (const float*)d_in[11];
  const float* b_rgcn   = (const float*)d_in[12];
  const float* gc_W1    = (const float*)d_in[13];
  const float* gc_W2    = (const float*)d_in[14];
  const float* gc_b     = (const float*)d_in[15];
  const float* Wm       = (const float*)d_in[16];
  const float* bm       = (const float*)d_in[17];
  const float* Wl       = (const float*)d_in[18];
  const float* bl       = (const float*)d_in[19];
  const float* Wsw      = (const float*)d_in[20];
  const float* bsw      = (const float*)d_in[21];
  const int*   speakers = (const int*)d_in[22];

  float* ws = (float*)d_ws;
  // Regions (float offsets), reused across phases (lifetimes audited):
  float* gates   = ws + 0L;          // 16.78M f: gates0/1 -> xrelbf -> xtrbf
  float* feats   = ws + 16777216L;   //  4.19M f: wih0bf/wih1bf -> attbf
  float* xbuf    = ws + 20971520L;   //  4.19M f: ubf -> xbf (lstm L1 direct) -> emT
  float* feats0  = ws + 25165824L;   //  4.19M f: f0bf -> h/hbf/aggbf -> embf
  float* scaleb  = ws + 29360128L;   //  1.05M f: scale -> logits -> hidden(lo)
  float* scoresb = ws + 30408704L;   //  1.05M f: wscT -> edge scores -> abf -> hidden(hi)
  float* wrelr   = ws + 31457280L;   //  1.05M f: wrel2t bf16
  float* hroot   = ws + 32505856L;   //  2.10M f: hroot -> h2
  uint*  wq      = (uint*)(ws + 34603008L);   // 262,144 dwords
  float* fsc     = ws + 34865152L;            // 4,096
  float* wTr     = ws + 34869248L;            // 524,288 f (transposed bf16 weights)

  ushort* ubf    = (ushort*)xbuf;
  ushort* wih0bf = (ushort*)feats;               // [0..1.05M f)
  ushort* wih1bf = (ushort*)(feats + 1048576L);  // [1.05..1.57M f)
  ushort* f0bf   = (ushort*)feats0;              // [0..2.1M f)
  ushort* xbf    = (ushort*)xbuf;                // [0..2.1M f) (ubf dead after L0 gemm)
  ushort* wrel2t = (ushort*)wrelr;
  ushort* wroott = (ushort*)wTr;                 // 131,072 us
  ushort* gcW1t  = wroott + 131072L;             //  65,536 us
  ushort* gcW2t  = gcW1t + 65536L;               //  65,536 us
  ushort* Wmt    = gcW2t + 65536L;               // 589,824 us
  ushort* Wlt    = Wmt + 589824L;                // 196,608 us
  ushort* wscT   = (ushort*)scoresb;             // 65,536 us (dead before edge_softmax)

  float*  hb      = feats0;                      // f32 [0..2.1M f)
  ushort* hbf     = (ushort*)(feats0 + 2097152L);
  ushort* aggbf   = (ushort*)(feats0 + 3145728L);
  ushort* embf    = (ushort*)feats0;             // 6.29M us [0..3.15M f)
  ushort* emT     = (ushort*)xbuf;               // 6.29M us [0..3.15M f) (xbf dead)
  ushort* xrelbf  = (ushort*)gates;              // 16.78M us [0..8.39M f)
  ushort* xtrbf   = (ushort*)gates;              // 6.29M us (xrelbf dead)
  ushort* abf     = (ushort*)scoresb;            // 1.05M us (edge scores dead)
  ushort* attbf   = (ushort*)feats;              // 6.29M us [0..3.15M f)

  float*  h2b     = hroot;
  float*  logitsb = scaleb;
  float*  hiddenb = scaleb;                      // 2.1M f spans scaleb+scoresb

  // --- weight prep ---
  pack_whh_i8_k<<<512, 256, 0, stream>>>(Whh0, wq, fsc);
  pack_whh_i8_k<<<512, 256, 0, stream>>>(Whh1, wq + 131072, fsc + 2048);
  cvt_bf16_k<<<8192, 256, 0, stream>>>(U, ubf);
  cvt_bf16_k<<<2048, 256, 0, stream>>>(Wih0, wih0bf);
  cvt_bf16_k<<<1024, 256, 0, stream>>>(Wih1, wih1bf);
  tp_bf16_k<<<dim3(8, 16), 256, 0, stream>>>(W_root, wroott, 512, 256);
  tp_bf16_k<<<dim3(8, 8), 256, 0, stream>>>(gc_W1, gcW1t, 256, 256);
  tp_bf16_k<<<dim3(8, 8), 256, 0, stream>>>(gc_W2, gcW2t, 256, 256);
  tp_bf16_k<<<dim3(24, 24), 256, 0, stream>>>(Wm, Wmt, 768, 768);
  tp_bf16_k<<<dim3(8, 24), 256, 0, stream>>>(Wl, Wlt, 768, 256);
  tp_bf16_k<<<dim3(4, 16), 256, 0, stream>>>(W_scalar, wscT, 512, 128);
  wrel_k<<<512, 256, 0, stream>>>(basis, comp, wrel2t);

  // --- layer 0 ---
  gemm_bf16_nt<true, false, false, false><<<dim3(8, 64, 2), 256, 0, stream>>>(
      ubf, wih0bf, b0, gates, 8192, 1024, 1024, 0L, 1048576L, 8388608L, 1024L);
  lstm4_k<<<128, 1024, 0, stream>>>(gates, wq, fsc, f0bf, 0);

  // --- layer 1 (writes x directly in b-major) ---
  gemm_bf16_nt<true, false, false, false><<<dim3(8, 64, 2), 256, 0, stream>>>(
      f0bf, wih1bf, b1, gates, 8192, 1024, 512, 0L, 524288L, 8388608L, 1024L);
  lstm4_k<<<128, 1024, 0, stream>>>(gates, wq + 131072, fsc + 2048, xbf, 1);

  // --- edge attention scores (A = xbf, rows (b*128+s)) ---
  gemm_bf16_nt<false, false, false, false><<<dim3(1, 64, 1), 256, 0, stream>>>(
      xbf, wscT, nullptr, scaleb, 8192, 128, 512, 0L, 0L, 0L, 0L);
  edge_softmax_k<<<8192, 128, 0, stream>>>(scaleb, scoresb);

  // --- RGCN ---
  gemm_bf16_nt<true, false, false, false><<<dim3(2, 64, 1), 256, 0, stream>>>(
      xbf, wroott, b_rgcn, hroot, 8192, 256, 512, 0L, 0L, 0L, 0L);
  gemm_bf16_nt<false, false, false, true><<<dim3(16, 64, 1), 256, 0, stream>>>(
      xbf, wrel2t, nullptr, xrelbf, 8192, 2048, 512, 0L, 0L, 0L, 0L);
  rgcn_gather_k<<<8192, 256, 0, stream>>>(xrelbf, scoresb, hroot, speakers, hb, hbf);

  // --- GraphConv ---
  agg_k<<<8192, 256, 0, stream>>>(hb, aggbf);
  gemm_bf16_nt<true, false, false, false><<<dim3(2, 64, 1), 256, 0, stream>>>(
      hbf, gcW1t, gc_b, h2b, 8192, 256, 256, 0L, 0L, 0L, 0L);
  gemm_bf16_nt<false, true, false, false><<<dim3(2, 64, 1), 256, 0, stream>>>(
      aggbf, gcW2t, nullptr, h2b, 8192, 256, 256, 0L, 0L, 0L, 0L);

  // --- matching attention ---
  em_k<<<8192, 256, 0, stream>>>(xbf, h2b, embf);
  gemm_bf16_nt<true, false, false, true><<<dim3(6, 64, 1), 256, 0, stream>>>(
      embf, Wmt, bm, xtrbf, 8192, 768, 768, 0L, 0L, 0L, 0L);
  emt_k<<<dim3(24, 4, 64), 256, 0, stream>>>(embf, emT);
  gemm_bf16_nt<false, false, false, false><<<dim3(1, 1, 64), 256, 0, stream>>>(
      xtrbf, embf, nullptr, logitsb, 128, 128, 768, 98304L, 98304L, 16384L, 0L);
  match_softmax_k<<<8192, 128, 0, stream>>>(logitsb, umask, abf);
  gemm_bf16_nt<false, false, false, true><<<dim3(6, 1, 64), 256, 0, stream>>>(
      abf, emT, nullptr, attbf, 128, 768, 128, 16384L, 98304L, 98304L, 0L);

  // --- classifier ---
  gemm_bf16_nt<true, false, true, false><<<dim3(2, 64, 1), 256, 0, stream>>>(
      attbf, Wlt, bl, hiddenb, 8192, 256, 768, 0L, 0L, 0L, 0L);
  final_k<<<2048, 256, 0, stream>>>(hiddenb, Wsw, bsw, (float*)d_out);
}

// Round 11
// 623.551 us; speedup vs baseline: 1.3583x; 1.0376x over previous
//
#include <hip/hip_runtime.h>
#include <cstdint>

// Model dims (fixed): L=128, B=64, DM=1024, H=256, F=512, HID=256, MEM=768,
// N=B*L=8192, NC=6, R=8, NB=30, WIN=10

typedef __attribute__((ext_vector_type(8))) short bf16x8;
typedef __attribute__((ext_vector_type(4))) float f32x4;

__device__ __forceinline__ void gload_lds16(const void* g, void* l) {
  __builtin_amdgcn_global_load_lds(
      (const __attribute__((address_space(1))) void*)g,
      (__attribute__((address_space(3))) void*)l, 16, 0, 0);
}

// ---------------------------------------------------------------------------
// bf16 NT MFMA GEMM (proven r10): 128x128x32 tile, 4 waves, global_load_lds.
// ---------------------------------------------------------------------------
template<bool HASBIAS, bool ACCUM, bool RELU, bool OUTBF>
__global__ __launch_bounds__(256) void gemm_bf16_nt(
    const ushort* __restrict__ A, const ushort* __restrict__ Bt,
    const float* __restrict__ bias, void* __restrict__ Cv,
    int M, int N, int K, long sA, long sB, long sC, long sBias)
{
  const int bz = blockIdx.z;
  A += (long)bz * sA;
  Bt += (long)bz * sB;
  if (HASBIAS) bias += (long)bz * sBias;
  float*  Cf = OUTBF ? nullptr : ((float*)Cv + (long)bz * sC);
  ushort* Cb = OUTBF ? ((ushort*)Cv + (long)bz * sC) : nullptr;

  const int bn = blockIdx.x * 128, bm = blockIdx.y * 128;

  __shared__ ushort As[128][32];
  __shared__ ushort Bs[128][32];

  const int tid = threadIdx.x;
  const int wave = tid >> 6, lane = tid & 63;
  const int wm = (wave >> 1) * 64, wn = (wave & 1) * 64;
  const int fr = lane & 15;
  const int fk = (lane >> 4) * 8;

  f32x4 acc[4][4];
#pragma unroll
  for (int i = 0; i < 4; ++i)
#pragma unroll
    for (int j = 0; j < 4; ++j) acc[i][j] = (f32x4){0.f, 0.f, 0.f, 0.f};

  const int f0 = wave * 2 * 64 + lane;
  const int f1 = f0 + 64;
  const int r0 = f0 >> 2, c0 = (f0 & 3) * 8;
  const int r1 = f1 >> 2, c1 = (f1 & 3) * 8;
  ushort* As0 = (ushort*)As + wave * 2 * 512;
  ushort* As1 = As0 + 512;
  ushort* Bs0 = (ushort*)Bs + wave * 2 * 512;
  ushort* Bs1 = Bs0 + 512;

  for (int k0 = 0; k0 < K; k0 += 32) {
    gload_lds16(A + (long)(bm + r0) * K + k0 + c0, As0);
    gload_lds16(A + (long)(bm + r1) * K + k0 + c1, As1);
    gload_lds16(Bt + (long)(bn + r0) * K + k0 + c0, Bs0);
    gload_lds16(Bt + (long)(bn + r1) * K + k0 + c1, Bs1);
    __syncthreads();

    bf16x8 af[4], bfr[4];
#pragma unroll
    for (int f = 0; f < 4; ++f) {
      af[f]  = *(const bf16x8*)&As[wm + f * 16 + fr][fk];
      bfr[f] = *(const bf16x8*)&Bs[wn + f * 16 + fr][fk];
    }
#pragma unroll
    for (int mf = 0; mf < 4; ++mf)
#pragma unroll
      for (int nf = 0; nf < 4; ++nf)
        acc[mf][nf] = __builtin_amdgcn_mfma_f32_16x16x32_bf16(
            af[mf], bfr[nf], acc[mf][nf], 0, 0, 0);
    __syncthreads();
  }

  float bv[4];
#pragma unroll
  for (int nf = 0; nf < 4; ++nf)
    bv[nf] = HASBIAS ? bias[bn + wn + nf * 16 + fr] : 0.f;

  const int crow0 = (lane >> 4) * 4;
#pragma unroll
  for (int mf = 0; mf < 4; ++mf)
#pragma unroll
    for (int r = 0; r < 4; ++r) {
      const long roff = (long)(bm + wm + mf * 16 + crow0 + r) * N + bn + wn;
#pragma unroll
      for (int nf = 0; nf < 4; ++nf) {
        float v = acc[mf][nf][r] + bv[nf];
        if (OUTBF) {
          unsigned u = __float_as_uint(v);
          u += 0x7fffu + ((u >> 16) & 1u);
          Cb[roff + nf * 16 + fr] = (ushort)(u >> 16);
        } else {
          if (ACCUM) v += Cf[roff + nf * 16 + fr];
          if (RELU) v = fmaxf(v, 0.f);
          Cf[roff + nf * 16 + fr] = v;
        }
      }
    }
}

// ---------------------------------------------------------------------------
// helpers
// ---------------------------------------------------------------------------
__device__ __forceinline__ unsigned short f2bf(float f) {
  unsigned u = __float_as_uint(f);
  u += 0x7fffu + ((u >> 16) & 1u);
  return (unsigned short)(u >> 16);
}
__device__ __forceinline__ float bf2f(ushort v) {
  return __uint_as_float(((unsigned)v) << 16);
}
__device__ __forceinline__ float fast_sig(float x) {
  return __builtin_amdgcn_rcpf(1.f + __expf(-x));
}
__device__ __forceinline__ float fast_tanh(float x) {
  return 2.f * fast_sig(2.f * x) - 1.f;
}

__device__ __forceinline__ int sdot4_(uint a, uint b, int c) {
#if __has_builtin(__builtin_amdgcn_sdot4)
  return __builtin_amdgcn_sdot4((int)a, (int)b, c, false);
#else
  int r = c;
  r += ((int)(a << 24) >> 24) * ((int)(b << 24) >> 24);
  r += ((int)(a << 16) >> 24) * ((int)(b << 16) >> 24);
  r += ((int)(a << 8)  >> 24) * ((int)(b << 8)  >> 24);
  r += ((int)a >> 24)         * ((int)b >> 24);
  return r;
#endif
}

// Fused f32->bf16 conversions: U (8192 blocks) + Wih0 (2048) + Wih1 (1024)
__global__ __launch_bounds__(256) void cvt_all_k(
    const float* __restrict__ U, ushort* __restrict__ ubf,
    const float* __restrict__ W0, ushort* __restrict__ w0,
    const float* __restrict__ W1, ushort* __restrict__ w1)
{
  const int bid = blockIdx.x;
  const float* src; ushort* dst; long base;
  if (bid < 8192)       { src = U;  dst = ubf; base = (long)bid * 1024; }
  else if (bid < 10240) { src = W0; dst = w0;  base = (long)(bid - 8192) * 1024; }
  else                  { src = W1; dst = w1;  base = (long)(bid - 10240) * 1024; }
  const long i = base + threadIdx.x * 4;
  float4 v = *(const float4*)(src + i);
  ushort4 o;
  o.x = f2bf(v.x); o.y = f2bf(v.y); o.z = f2bf(v.z); o.w = f2bf(v.w);
  *(ushort4*)(dst + i) = o;
}

// Fused transpose+bf16 for all 6 weight matrices (static job table)
__global__ __launch_bounds__(256) void tp_all_k(
    const float* __restrict__ s0, ushort* __restrict__ d0,   // W_root 512x256
    const float* __restrict__ s1, ushort* __restrict__ d1,   // gc_W1 256x256
    const float* __restrict__ s2, ushort* __restrict__ d2,   // gc_W2 256x256
    const float* __restrict__ s3, ushort* __restrict__ d3,   // Wm 768x768
    const float* __restrict__ s4, ushort* __restrict__ d4,   // Wl 768x256
    const float* __restrict__ s5, ushort* __restrict__ d5)   // W_scalar 512x128
{
  __shared__ float tile[32][33];
  const int bid = blockIdx.x;
  const float* src; ushort* dst; int R, C, gx, local;
  if (bid < 128)       { src = s0; dst = d0; R = 512; C = 256; gx = 8;  local = bid; }
  else if (bid < 192)  { src = s1; dst = d1; R = 256; C = 256; gx = 8;  local = bid - 128; }
  else if (bid < 256)  { src = s2; dst = d2; R = 256; C = 256; gx = 8;  local = bid - 192; }
  else if (bid < 832)  { src = s3; dst = d3; R = 768; C = 768; gx = 24; local = bid - 256; }
  else if (bid < 1024) { src = s4; dst = d4; R = 768; C = 256; gx = 8;  local = bid - 832; }
  else                 { src = s5; dst = d5; R = 512; C = 128; gx = 4;  local = bid - 1024; }
  const int c0 = (local % gx) * 32, r0 = (local / gx) * 32;
  const int tx = threadIdx.x & 31, ty = threadIdx.x >> 5;
#pragma unroll
  for (int j = 0; j < 4; ++j)
    tile[ty + j * 8][tx] = src[(long)(r0 + ty + j * 8) * C + c0 + tx];
  __syncthreads();
#pragma unroll
  for (int j = 0; j < 4; ++j)
    dst[(long)(c0 + ty + j * 8) * R + r0 + tx] = f2bf(tile[tx][ty + j * 8]);
}

// Fused Whh pack (both layers): (2,1024,256) f32 -> int8 dwords + scales
__global__ __launch_bounds__(256) void pack_whh_all_k(
    const float* __restrict__ Whh0, const float* __restrict__ Whh1,
    uint* __restrict__ Wq, float* __restrict__ fscale)
{
  const int wid = (blockIdx.x * 256 + threadIdx.x) >> 6;  // 0..4095
  const int lane = threadIdx.x & 63;
  const int l = wid >> 11;
  const int wid2 = wid & 2047;
  const int d = wid2 >> 10, gi = wid2 & 1023;
  const float* Whh = l ? Whh1 : Whh0;
  const float* row = Whh + ((long)d * 1024 + gi) * 256 + lane * 4;
  float v0 = row[0], v1 = row[1], v2 = row[2], v3 = row[3];
  float am = fmaxf(fmaxf(fabsf(v0), fabsf(v1)), fmaxf(fabsf(v2), fabsf(v3)));
#pragma unroll
  for (int off = 32; off > 0; off >>= 1) am = fmaxf(am, __shfl_xor(am, off, 64));
  am = fmaxf(am, 1e-12f);
  const float inv = 127.f / am;
  int q0 = __float2int_rn(v0 * inv), q1 = __float2int_rn(v1 * inv);
  int q2 = __float2int_rn(v2 * inv), q3 = __float2int_rn(v3 * inv);
  uint w = (uint)(q0 & 255) | ((uint)(q1 & 255) << 8) |
           ((uint)(q2 & 255) << 16) | ((uint)(q3 & 255) << 24);
  Wq[(long)l * 131072 + ((long)d * 64 + lane) * 1024 + gi] = w;
  if (lane == 0) fscale[l * 2048 + d * 1024 + gi] = am / 127.f;
}

// ---------------------------------------------------------------------------
// LSTM v4 (proven): int8 weights streamed from L2, int8 h via LDS broadcast,
// sdot4; bf16 output. 128 WGs = (dir, b); 1024 thr = (gate, i).
// ---------------------------------------------------------------------------
__global__ __launch_bounds__(1024) void lstm4_k(
    const float* __restrict__ Xg,
    const uint* __restrict__ Wq,
    const float* __restrict__ fscale,
    ushort* __restrict__ out,
    int bmajor)
{
  const int bx = blockIdx.x;
  const int d = bx >> 6, b = bx & 63;
  const int tid = threadIdx.x;

  __shared__ uint hq[2][64];
  __shared__ float preactF[1024];

  uint w[64];
  const uint* wrow = Wq + (long)d * 65536 + tid;
#pragma unroll
  for (int k4 = 0; k4 < 64; ++k4) w[k4] = wrow[k4 * 1024];

  if (tid < 128) ((uint*)hq)[tid] = 0u;

  const float fsc = fscale[d * 1024 + tid] * (1.0f / 127.0f);
  const float* Xd = Xg + (long)d * 8192 * 1024;

  float c = 0.f;
  float x0 = 0.f, x1 = 0.f, x2 = 0.f, x3 = 0.f;
  if (tid < 256) {
    const float* xr = Xd + ((long)((d ? 127 : 0) * 64 + b)) * 1024;
    x0 = xr[tid]; x1 = xr[tid + 256]; x2 = xr[tid + 512]; x3 = xr[tid + 768];
  }
  __syncthreads();

  int cur = 0;
  for (int step = 0; step < 128; ++step) {
    const int t = d ? 127 - step : step;

    float n0 = 0.f, n1 = 0.f, n2 = 0.f, n3 = 0.f;
    if (tid < 256 && step + 1 < 128) {
      const float* xr = Xd + ((long)((d ? 126 - step : step + 1) * 64 + b)) * 1024;
      n0 = xr[tid]; n1 = xr[tid + 256]; n2 = xr[tid + 512]; n3 = xr[tid + 768];
    }

    int acc = 0;
    const uint4* hrow = (const uint4*)hq[cur];
#pragma unroll
    for (int k16 = 0; k16 < 16; ++k16) {
      uint4 h4 = hrow[k16];
      acc = sdot4_(w[k16 * 4 + 0], h4.x, acc);
      acc = sdot4_(w[k16 * 4 + 1], h4.y, acc);
      acc = sdot4_(w[k16 * 4 + 2], h4.z, acc);
      acc = sdot4_(w[k16 * 4 + 3], h4.w, acc);
    }
    preactF[tid] = (float)acc * fsc;
    __syncthreads();

    if (tid < 256) {
      float p0 = x0 + preactF[tid];
      float p1 = x1 + preactF[tid + 256];
      float p2 = x2 + preactF[tid + 512];
      float p3 = x3 + preactF[tid + 768];
      const float ig = fast_sig(p0), fg = fast_sig(p1);
      const float gg = fast_tanh(p2), og = fast_sig(p3);
      c = fg * c + ig * gg;
      const float h = og * fast_tanh(c);
      const long row = bmajor ? ((long)b * 128 + t) : ((long)t * 64 + b);
      out[row * 512 + (d << 8) + tid] = f2bf(h);
      ((char*)hq[cur ^ 1])[tid] = (char)__float2int_rn(h * 127.f);
      x0 = n0; x1 = n1; x2 = n2; x3 = n3;
    }
    __syncthreads();
    cur ^= 1;
  }
}

// W_rel basis combination -> bf16 transposed (N=r*256+o rows, K=f cols)
__global__ __launch_bounds__(256) void wrel_k(const float* __restrict__ basis,
                                              const float* __restrict__ comp,
                                              ushort* __restrict__ wrel2t) {
  const int f = blockIdx.x;     // 0..511
  const int o = threadIdx.x;    // 0..255
  __shared__ float cs[240];
  if (o < 240) cs[o] = comp[o];
  __syncthreads();
  float acc[8];
#pragma unroll
  for (int r = 0; r < 8; ++r) acc[r] = 0.f;
  for (int bb = 0; bb < 30; ++bb) {
    const float v = basis[((long)bb * 512 + f) * 256 + o];
#pragma unroll
    for (int r = 0; r < 8; ++r) acc[r] = fmaf(cs[r * 30 + bb], v, acc[r]);
  }
#pragma unroll
  for (int r = 0; r < 8; ++r)
    wrel2t[((long)(r * 256 + o)) * 512 + f] = f2bf(acc[r]);
}

// ---------------------------------------------------------------------------
// RGCN gather FUSED with edge-attention softmax. Block (b,t), 256 threads.
// scale rows are (b*128+s), cols t. scores_s = e_s*f_s / sum(e*f), f=1 in
// window else 1e-10 (esum cancels algebraically).
// Writes hbf (bf16) only.
// ---------------------------------------------------------------------------
__global__ __launch_bounds__(256) void rgcn_fused_k(
    const float* __restrict__ scale, const ushort* __restrict__ xrel,
    const float* __restrict__ hroot, const int* __restrict__ spk,
    ushort* __restrict__ hbf)
{
  const int n = blockIdx.x;
  const int b = n >> 7, t = n & 127;
  const int o = threadIdx.x;
  const int lo = max(t - 10, 0), hi = min(t + 10, 127);
  const int cnt = hi - lo + 1;

  __shared__ float sc[128], red[128];
  __shared__ int spks[21];
  __shared__ int spkt_s;

  if (o < 128) {
    const float v = scale[((long)(b * 128 + o)) * 128 + t];
    sc[o] = v; red[o] = v;
  }
  if (o == 0) spkt_s = spk[t * 64 + b];
  if (o >= 128 && o - 128 < cnt) spks[o - 128] = spk[(lo + o - 128) * 64 + b];
  __syncthreads();
  for (int off = 64; off > 0; off >>= 1) {
    if (o < off) red[o] = fmaxf(red[o], red[o + off]);
    __syncthreads();
  }
  const float m = red[0];
  __syncthreads();
  if (o < 128) {
    const float e = expf(sc[o] - m);
    sc[o] = e;
    const int dd = o - t;
    const bool inwin = (dd <= 10) && (dd >= -10);
    red[o] = e * (inwin ? 1.0f : 1e-10f);
  }
  __syncthreads();
  for (int off = 64; off > 0; off >>= 1) {
    if (o < off) red[o] += red[o + off];
    __syncthreads();
  }
  const float inv_msum = 1.0f / red[0];
  __syncthreads();

  const int spkt = spkt_s;
  float acc = hroot[(long)n * 256 + o];
  for (int q = 0; q < cnt; ++q) {
    const int s = lo + q;
    const float wv = sc[s] * inv_msum;
    const int et = spkt * 4 + spks[q] * 2 + ((t < s) ? 0 : 1);
    acc = fmaf(bf2f(xrel[(((long)(b * 128 + s)) * 8 + et) * 256 + o]), wv, acc);
  }
  hbf[(long)n * 256 + o] = f2bf(acc);
}

// GraphConv neighbor aggregation (reads bf16 h) -> bf16
__global__ __launch_bounds__(256) void agg_k(const ushort* __restrict__ hbf,
                                             ushort* __restrict__ aggbf) {
  const int n = blockIdx.x;
  const int b = n >> 7, t = n & 127;
  const int o = threadIdx.x;
  const int lo = max(t - 10, 0), hi = min(t + 10, 127);
  float acc = 0.f;
  for (int s = lo; s <= hi; ++s) acc += bf2f(hbf[((long)(b * 128 + s)) * 256 + o]);
  aggbf[(long)n * 256 + o] = f2bf(acc);
}

// embf = concat(xbf, bf16(h2))
__global__ __launch_bounds__(256) void em_k(const ushort* __restrict__ xbf,
                                            const float* __restrict__ h2,
                                            ushort* __restrict__ embf) {
  const int n = blockIdx.x;
  const int tid = threadIdx.x;
  embf[(long)n * 768 + tid] = xbf[(long)n * 512 + tid];
  embf[(long)n * 768 + 256 + tid] = xbf[(long)n * 512 + 256 + tid];
  embf[(long)n * 768 + 512 + tid] = f2bf(h2[(long)n * 256 + tid]);
}

// Batched ushort transpose: dst[b](C x R) = src[b](R x C)^T, R=128, C=768.
__global__ __launch_bounds__(256) void emt_k(const ushort* __restrict__ src,
                                             ushort* __restrict__ dst) {
  __shared__ ushort tile[32][33];
  const int c0 = blockIdx.x * 32;
  const int r0 = blockIdx.y * 32;
  const int b = blockIdx.z;
  const ushort* s = src + (long)b * 98304;
  ushort* d = dst + (long)b * 98304;
  const int tx = threadIdx.x & 31, ty = threadIdx.x >> 5;
#pragma unroll
  for (int j = 0; j < 4; ++j)
    tile[ty + j * 8][tx] = s[(long)(r0 + ty + j * 8) * 768 + c0 + tx];
  __syncthreads();
#pragma unroll
  for (int j = 0; j < 4; ++j)
    d[(long)(c0 + ty + j * 8) * 128 + r0 + tx] = tile[tx][ty + j * 8];
}

// Matching attention probs: logits f32 in, bf16 a out
__global__ __launch_bounds__(128) void match_softmax_k(const float* __restrict__ logits,
                                                       const float* __restrict__ umask,
                                                       ushort* __restrict__ abf) {
  const int bx = blockIdx.x;           // b*128 + t
  const int b = bx >> 7;
  const int s = threadIdx.x;
  __shared__ float red[128];
  const float* row = logits + (long)bx * 128;
  const float um = umask[b * 128 + s];
  const float v = tanhf(row[s] * um * um);
  red[s] = v; __syncthreads();
  for (int off = 64; off > 0; off >>= 1) { if (s < off) red[s] = fmaxf(red[s], red[s + off]); __syncthreads(); }
  const float m = red[0]; __syncthreads();
  const float e = expf(v - m);
  red[s] = e; __syncthreads();
  for (int off = 64; off > 0; off >>= 1) { if (s < off) red[s] += red[s + off]; __syncthreads(); }
  const float es = red[0]; __syncthreads();
  const float p = (e / es) * um;
  red[s] = p; __syncthreads();
  for (int off = 64; off > 0; off >>= 1) { if (s < off) red[s] += red[s + off]; __syncthreads(); }
  const float ps = red[0];
  abf[(long)bx * 128 + s] = f2bf(p / ps);
}

__global__ __launch_bounds__(256) void final_k(const float* __restrict__ hidden,
                                               const float* __restrict__ Ws,
                                               const float* __restrict__ bs,
                                               float* __restrict__ out) {
  __shared__ float wsl[256 * 6];
  const int tid = threadIdx.x;
#pragma unroll
  for (int j = 0; j < 6; ++j) wsl[tid * 6 + j] = Ws[tid * 6 + j];
  __syncthreads();
  const int wave = tid >> 6, lane = tid & 63;
  const int n = blockIdx.x * 4 + wave;
  const float4 hv = *(const float4*)&hidden[(long)n * 256 + lane * 4];
  const float hvv[4] = {hv.x, hv.y, hv.z, hv.w};
  float a[6];
#pragma unroll
  for (int c = 0; c < 6; ++c) a[c] = 0.f;
#pragma unroll
  for (int j = 0; j < 4; ++j)
#pragma unroll
    for (int c = 0; c < 6; ++c)
      a[c] = fmaf(hvv[j], wsl[(lane * 4 + j) * 6 + c], a[c]);
#pragma unroll
  for (int off = 32; off > 0; off >>= 1)
#pragma unroll
    for (int c = 0; c < 6; ++c)
      a[c] += __shfl_xor(a[c], off, 64);
  if (lane == 0) {
    float v[6], m = -1e30f;
#pragma unroll
    for (int c = 0; c < 6; ++c) { v[c] = a[c] + bs[c]; m = fmaxf(m, v[c]); }
    float sum = 0.f;
#pragma unroll
    for (int c = 0; c < 6; ++c) sum += expf(v[c] - m);
    const float lse = m + logf(sum);
#pragma unroll
    for (int c = 0; c < 6; ++c) out[(long)n * 6 + c] = v[c] - lse;
  }
}

// ---------------------------------------------------------------------------
// Orchestration
// ---------------------------------------------------------------------------
extern "C" void kernel_launch(void* const* d_in, const int* in_sizes, int n_in,
                              void* d_out, int out_size, void* d_ws, size_t ws_size,
                              hipStream_t stream) {
  const float* U        = (const float*)d_in[0];
  const float* umask    = (const float*)d_in[1];
  const float* Wih0     = (const float*)d_in[2];
  const float* Whh0     = (const float*)d_in[3];
  const float* b0       = (const float*)d_in[4];
  const float* Wih1     = (const float*)d_in[5];
  const float* Whh1     = (const float*)d_in[6];
  const float* b1       = (const float*)d_in[7];
  const float* W_scalar = (const float*)d_in[8];
  const float* basis    = (const float*)d_in[9];
  const float* comp     = (const float*)d_in[10];
  const float* W_root   = (const float*)d_in[11];
  const float* b_rgcn   = (const float*)d_in[12];
  const float* gc_W1    = (const float*)d_in[13];
  const float* gc_W2    = (const float*)d_in[14];
  const float* gc_b     = (const float*)d_in[15];
  const float* Wm       = (const float*)d_in[16];
  const float* bm       = (const float*)d_in[17];
  const float* Wl       = (const float*)d_in[18];
  const float* bl       = (const float*)d_in[19];
  const float* Wsw      = (const float*)d_in[20];
  const float* bsw      = (const float*)d_in[21];
  const int*   speakers = (const int*)d_in[22];

  float* ws = (float*)d_ws;
  float* gates   = ws + 0L;          // 16.78M f: gates0/1 -> xrelbf -> xtrbf
  float* feats   = ws + 16777216L;   //  4.19M f: wih0bf/wih1bf -> attbf
  float* xbuf    = ws + 20971520L;   //  4.19M f: ubf -> xbf -> emT
  float* feats0  = ws + 25165824L;   //  4.19M f: f0bf -> hbf/aggbf -> embf
  float* scaleb  = ws + 29360128L;   //  1.05M f: scale -> logits -> hidden(lo)
  float* scoresb = ws + 30408704L;   //  1.05M f: wscT -> abf -> hidden(hi)
  float* wrelr   = ws + 31457280L;   //  1.05M f: wrel2t bf16
  float* hroot   = ws + 32505856L;   //  2.10M f: hroot -> h2
  uint*  wq      = (uint*)(ws + 34603008L);   // 262,144 dwords
  float* fsc     = ws + 34865152L;            // 4,096
  float* wTr     = ws + 34869248L;            // 524,288 f

  ushort* ubf    = (ushort*)xbuf;
  ushort* wih0bf = (ushort*)feats;
  ushort* wih1bf = (ushort*)(feats + 1048576L);
  ushort* f0bf   = (ushort*)feats0;
  ushort* xbf    = (ushort*)xbuf;
  ushort* wrel2t = (ushort*)wrelr;
  ushort* wroott = (ushort*)wTr;                 // 131,072 us
  ushort* gcW1t  = wroott + 131072L;             //  65,536 us
  ushort* gcW2t  = gcW1t + 65536L;               //  65,536 us
  ushort* Wmt    = gcW2t + 65536L;               // 589,824 us
  ushort* Wlt    = Wmt + 589824L;                // 196,608 us
  ushort* wscT   = (ushort*)scoresb;             // 65,536 us (dead after scale gemm)

  ushort* hbf     = (ushort*)(feats0 + 2097152L);
  ushort* aggbf   = (ushort*)(feats0 + 3145728L);
  ushort* embf    = (ushort*)feats0;
  ushort* emT     = (ushort*)xbuf;
  ushort* xrelbf  = (ushort*)gates;
  ushort* xtrbf   = (ushort*)gates;
  ushort* abf     = (ushort*)scoresb;
  ushort* attbf   = (ushort*)feats;

  float*  h2b     = hroot;
  float*  logitsb = scaleb;
  float*  hiddenb = scaleb;

  // --- weight prep (4 dispatches) ---
  pack_whh_all_k<<<1024, 256, 0, stream>>>(Whh0, Whh1, wq, fsc);
  cvt_all_k<<<11264, 256, 0, stream>>>(U, ubf, Wih0, wih0bf, Wih1, wih1bf);
  tp_all_k<<<1088, 256, 0, stream>>>(W_root, wroott, gc_W1, gcW1t, gc_W2, gcW2t,
                                     Wm, Wmt, Wl, Wlt, W_scalar, wscT);
  wrel_k<<<512, 256, 0, stream>>>(basis, comp, wrel2t);

  // --- layer 0 ---
  gemm_bf16_nt<true, false, false, false><<<dim3(8, 64, 2), 256, 0, stream>>>(
      ubf, wih0bf, b0, gates, 8192, 1024, 1024, 0L, 1048576L, 8388608L, 1024L);
  lstm4_k<<<128, 1024, 0, stream>>>(gates, wq, fsc, f0bf, 0);

  // --- layer 1 (writes x directly in b-major) ---
  gemm_bf16_nt<true, false, false, false><<<dim3(8, 64, 2), 256, 0, stream>>>(
      f0bf, wih1bf, b1, gates, 8192, 1024, 512, 0L, 524288L, 8388608L, 1024L);
  lstm4_k<<<128, 1024, 0, stream>>>(gates, wq + 131072, fsc + 2048, xbf, 1);

  // --- edge scale + RGCN ---
  gemm_bf16_nt<false, false, false, false><<<dim3(1, 64, 1), 256, 0, stream>>>(
      xbf, wscT, nullptr, scaleb, 8192, 128, 512, 0L, 0L, 0L, 0L);
  gemm_bf16_nt<true, false, false, false><<<dim3(2, 64, 1), 256, 0, stream>>>(
      xbf, wroott, b_rgcn, hroot, 8192, 256, 512, 0L, 0L, 0L, 0L);
  gemm_bf16_nt<false, false, false, true><<<dim3(16, 64, 1), 256, 0, stream>>>(
      xbf, wrel2t, nullptr, xrelbf, 8192, 2048, 512, 0L, 0L, 0L, 0L);
  rgcn_fused_k<<<8192, 256, 0, stream>>>(scaleb, xrelbf, hroot, speakers, hbf);

  // --- GraphConv ---
  agg_k<<<8192, 256, 0, stream>>>(hbf, aggbf);
  gemm_bf16_nt<true, false, false, false><<<dim3(2, 64, 1), 256, 0, stream>>>(
      hbf, gcW1t, gc_b, h2b, 8192, 256, 256, 0L, 0L, 0L, 0L);
  gemm_bf16_nt<false, true, false, false><<<dim3(2, 64, 1), 256, 0, stream>>>(
      aggbf, gcW2t, nullptr, h2b, 8192, 256, 256, 0L, 0L, 0L, 0L);

  // --- matching attention ---
  em_k<<<8192, 256, 0, stream>>>(xbf, h2b, embf);
  gemm_bf16_nt<true, false, false, true><<<dim3(6, 64, 1), 256, 0, stream>>>(
      embf, Wmt, bm, xtrbf, 8192, 768, 768, 0L, 0L, 0L, 0L);
  emt_k<<<dim3(24, 4, 64), 256, 0, stream>>>(embf, emT);
  gemm_bf16_nt<false, false, false, false><<<dim3(1, 1, 64), 256, 0, stream>>>(
      xtrbf, embf, nullptr, logitsb, 128, 128, 768, 98304L, 98304L, 16384L, 0L);
  match_softmax_k<<<8192, 128, 0, stream>>>(logitsb, umask, abf);
  gemm_bf16_nt<false, false, false, true><<<dim3(6, 1, 64), 256, 0, stream>>>(
      abf, emT, nullptr, attbf, 128, 768, 128, 16384L, 98304L, 98304L, 0L);

  // --- classifier ---
  gemm_bf16_nt<true, false, true, false><<<dim3(2, 64, 1), 256, 0, stream>>>(
      attbf, Wlt, bl, hiddenb, 8192, 256, 768, 0L, 0L, 0L, 0L);
  final_k<<<2048, 256, 0, stream>>>(hiddenb, Wsw, bsw, (float*)d_out);
}

// Round 12
// 621.877 us; speedup vs baseline: 1.3619x; 1.0027x over previous
//
#include <hip/hip_runtime.h>
#include <cstdint>

// Model dims (fixed): L=128, B=64, DM=1024, H=256, F=512, HID=256, MEM=768,
// N=B*L=8192, NC=6, R=8, NB=30, WIN=10

typedef __attribute__((ext_vector_type(8))) short bf16x8;
typedef __attribute__((ext_vector_type(4))) float f32x4;

__device__ __forceinline__ void gload_lds16(const void* g, void* l) {
  __builtin_amdgcn_global_load_lds(
      (const __attribute__((address_space(1))) void*)g,
      (__attribute__((address_space(3))) void*)l, 16, 0, 0);
}

// ---------------------------------------------------------------------------
// bf16 NT MFMA GEMM (proven r10): 128x128x32 tile, 4 waves, global_load_lds.
// ---------------------------------------------------------------------------
template<bool HASBIAS, bool ACCUM, bool RELU, bool OUTBF>
__global__ __launch_bounds__(256) void gemm_bf16_nt(
    const ushort* __restrict__ A, const ushort* __restrict__ Bt,
    const float* __restrict__ bias, void* __restrict__ Cv,
    int M, int N, int K, long sA, long sB, long sC, long sBias)
{
  const int bz = blockIdx.z;
  A += (long)bz * sA;
  Bt += (long)bz * sB;
  if (HASBIAS) bias += (long)bz * sBias;
  float*  Cf = OUTBF ? nullptr : ((float*)Cv + (long)bz * sC);
  ushort* Cb = OUTBF ? ((ushort*)Cv + (long)bz * sC) : nullptr;

  const int bn = blockIdx.x * 128, bm = blockIdx.y * 128;

  __shared__ ushort As[128][32];
  __shared__ ushort Bs[128][32];

  const int tid = threadIdx.x;
  const int wave = tid >> 6, lane = tid & 63;
  const int wm = (wave >> 1) * 64, wn = (wave & 1) * 64;
  const int fr = lane & 15;
  const int fk = (lane >> 4) * 8;

  f32x4 acc[4][4];
#pragma unroll
  for (int i = 0; i < 4; ++i)
#pragma unroll
    for (int j = 0; j < 4; ++j) acc[i][j] = (f32x4){0.f, 0.f, 0.f, 0.f};

  const int f0 = wave * 2 * 64 + lane;
  const int f1 = f0 + 64;
  const int r0 = f0 >> 2, c0 = (f0 & 3) * 8;
  const int r1 = f1 >> 2, c1 = (f1 & 3) * 8;
  ushort* As0 = (ushort*)As + wave * 2 * 512;
  ushort* As1 = As0 + 512;
  ushort* Bs0 = (ushort*)Bs + wave * 2 * 512;
  ushort* Bs1 = Bs0 + 512;

  for (int k0 = 0; k0 < K; k0 += 32) {
    gload_lds16(A + (long)(bm + r0) * K + k0 + c0, As0);
    gload_lds16(A + (long)(bm + r1) * K + k0 + c1, As1);
    gload_lds16(Bt + (long)(bn + r0) * K + k0 + c0, Bs0);
    gload_lds16(Bt + (long)(bn + r1) * K + k0 + c1, Bs1);
    __syncthreads();

    bf16x8 af[4], bfr[4];
#pragma unroll
    for (int f = 0; f < 4; ++f) {
      af[f]  = *(const bf16x8*)&As[wm + f * 16 + fr][fk];
      bfr[f] = *(const bf16x8*)&Bs[wn + f * 16 + fr][fk];
    }
#pragma unroll
    for (int mf = 0; mf < 4; ++mf)
#pragma unroll
      for (int nf = 0; nf < 4; ++nf)
        acc[mf][nf] = __builtin_amdgcn_mfma_f32_16x16x32_bf16(
            af[mf], bfr[nf], acc[mf][nf], 0, 0, 0);
    __syncthreads();
  }

  float bv[4];
#pragma unroll
  for (int nf = 0; nf < 4; ++nf)
    bv[nf] = HASBIAS ? bias[bn + wn + nf * 16 + fr] : 0.f;

  const int crow0 = (lane >> 4) * 4;
#pragma unroll
  for (int mf = 0; mf < 4; ++mf)
#pragma unroll
    for (int r = 0; r < 4; ++r) {
      const long roff = (long)(bm + wm + mf * 16 + crow0 + r) * N + bn + wn;
#pragma unroll
      for (int nf = 0; nf < 4; ++nf) {
        float v = acc[mf][nf][r] + bv[nf];
        if (OUTBF) {
          unsigned u = __float_as_uint(v);
          u += 0x7fffu + ((u >> 16) & 1u);
          Cb[roff + nf * 16 + fr] = (ushort)(u >> 16);
        } else {
          if (ACCUM) v += Cf[roff + nf * 16 + fr];
          if (RELU) v = fmaxf(v, 0.f);
          Cf[roff + nf * 16 + fr] = v;
        }
      }
    }
}

// ---------------------------------------------------------------------------
// helpers
// ---------------------------------------------------------------------------
__device__ __forceinline__ unsigned short f2bf(float f) {
  unsigned u = __float_as_uint(f);
  u += 0x7fffu + ((u >> 16) & 1u);
  return (unsigned short)(u >> 16);
}
__device__ __forceinline__ float bf2f(ushort v) {
  return __uint_as_float(((unsigned)v) << 16);
}
__device__ __forceinline__ float fast_sig(float x) {
  return __builtin_amdgcn_rcpf(1.f + __expf(-x));
}
__device__ __forceinline__ float fast_tanh(float x) {
  return 2.f * fast_sig(2.f * x) - 1.f;
}

__device__ __forceinline__ int sdot4_(uint a, uint b, int c) {
#if __has_builtin(__builtin_amdgcn_sdot4)
  return __builtin_amdgcn_sdot4((int)a, (int)b, c, false);
#else
  int r = c;
  r += ((int)(a << 24) >> 24) * ((int)(b << 24) >> 24);
  r += ((int)(a << 16) >> 24) * ((int)(b << 16) >> 24);
  r += ((int)(a << 8)  >> 24) * ((int)(b << 8)  >> 24);
  r += ((int)a >> 24)         * ((int)b >> 24);
  return r;
#endif
}

// Fused f32->bf16 conversions: U (8192 blocks) + Wih0 (2048) + Wih1 (1024)
__global__ __launch_bounds__(256) void cvt_all_k(
    const float* __restrict__ U, ushort* __restrict__ ubf,
    const float* __restrict__ W0, ushort* __restrict__ w0,
    const float* __restrict__ W1, ushort* __restrict__ w1)
{
  const int bid = blockIdx.x;
  const float* src; ushort* dst; long base;
  if (bid < 8192)       { src = U;  dst = ubf; base = (long)bid * 1024; }
  else if (bid < 10240) { src = W0; dst = w0;  base = (long)(bid - 8192) * 1024; }
  else                  { src = W1; dst = w1;  base = (long)(bid - 10240) * 1024; }
  const long i = base + threadIdx.x * 4;
  float4 v = *(const float4*)(src + i);
  ushort4 o;
  o.x = f2bf(v.x); o.y = f2bf(v.y); o.z = f2bf(v.z); o.w = f2bf(v.w);
  *(ushort4*)(dst + i) = o;
}

// Fused transpose+bf16 for all 6 weight matrices (static job table)
__global__ __launch_bounds__(256) void tp_all_k(
    const float* __restrict__ s0, ushort* __restrict__ d0,   // W_root 512x256
    const float* __restrict__ s1, ushort* __restrict__ d1,   // gc_W1 256x256
    const float* __restrict__ s2, ushort* __restrict__ d2,   // gc_W2 256x256
    const float* __restrict__ s3, ushort* __restrict__ d3,   // Wm 768x768
    const float* __restrict__ s4, ushort* __restrict__ d4,   // Wl 768x256
    const float* __restrict__ s5, ushort* __restrict__ d5)   // W_scalar 512x128
{
  __shared__ float tile[32][33];
  const int bid = blockIdx.x;
  const float* src; ushort* dst; int R, C, gx, local;
  if (bid < 128)       { src = s0; dst = d0; R = 512; C = 256; gx = 8;  local = bid; }
  else if (bid < 192)  { src = s1; dst = d1; R = 256; C = 256; gx = 8;  local = bid - 128; }
  else if (bid < 256)  { src = s2; dst = d2; R = 256; C = 256; gx = 8;  local = bid - 192; }
  else if (bid < 832)  { src = s3; dst = d3; R = 768; C = 768; gx = 24; local = bid - 256; }
  else if (bid < 1024) { src = s4; dst = d4; R = 768; C = 256; gx = 8;  local = bid - 832; }
  else                 { src = s5; dst = d5; R = 512; C = 128; gx = 4;  local = bid - 1024; }
  const int c0 = (local % gx) * 32, r0 = (local / gx) * 32;
  const int tx = threadIdx.x & 31, ty = threadIdx.x >> 5;
#pragma unroll
  for (int j = 0; j < 4; ++j)
    tile[ty + j * 8][tx] = src[(long)(r0 + ty + j * 8) * C + c0 + tx];
  __syncthreads();
#pragma unroll
  for (int j = 0; j < 4; ++j)
    dst[(long)(c0 + ty + j * 8) * R + r0 + tx] = f2bf(tile[tx][ty + j * 8]);
}

// Fused Whh pack (both layers): (2,1024,256) f32 -> int8 dwords + scales
__global__ __launch_bounds__(256) void pack_whh_all_k(
    const float* __restrict__ Whh0, const float* __restrict__ Whh1,
    uint* __restrict__ Wq, float* __restrict__ fscale)
{
  const int wid = (blockIdx.x * 256 + threadIdx.x) >> 6;  // 0..4095
  const int lane = threadIdx.x & 63;
  const int l = wid >> 11;
  const int wid2 = wid & 2047;
  const int d = wid2 >> 10, gi = wid2 & 1023;
  const float* Whh = l ? Whh1 : Whh0;
  const float* row = Whh + ((long)d * 1024 + gi) * 256 + lane * 4;
  float v0 = row[0], v1 = row[1], v2 = row[2], v3 = row[3];
  float am = fmaxf(fmaxf(fabsf(v0), fabsf(v1)), fmaxf(fabsf(v2), fabsf(v3)));
#pragma unroll
  for (int off = 32; off > 0; off >>= 1) am = fmaxf(am, __shfl_xor(am, off, 64));
  am = fmaxf(am, 1e-12f);
  const float inv = 127.f / am;
  int q0 = __float2int_rn(v0 * inv), q1 = __float2int_rn(v1 * inv);
  int q2 = __float2int_rn(v2 * inv), q3 = __float2int_rn(v3 * inv);
  uint w = (uint)(q0 & 255) | ((uint)(q1 & 255) << 8) |
           ((uint)(q2 & 255) << 16) | ((uint)(q3 & 255) << 24);
  Wq[(long)l * 131072 + ((long)d * 64 + lane) * 1024 + gi] = w;
  if (lane == 0) fscale[l * 2048 + d * 1024 + gi] = am / 127.f;
}

// ---------------------------------------------------------------------------
// LSTM v4r: identical math to proven lstm4, but weight dwords are FORCED into
// VGPRs via asm liveness barriers (compiler otherwise re-streams from L2
// every step — VGPR_Count 52 proved the w[64] loads were sunk into the loop).
// 52 + 64 = ~116 VGPR <= 128 budget at 16 waves/WG (4 waves/SIMD).
// ---------------------------------------------------------------------------
__global__ __launch_bounds__(1024) void lstm4_k(
    const float* __restrict__ Xg,
    const uint* __restrict__ Wq,
    const float* __restrict__ fscale,
    ushort* __restrict__ out,
    int bmajor)
{
  const int bx = blockIdx.x;
  const int d = bx >> 6, b = bx & 63;
  const int tid = threadIdx.x;

  __shared__ uint hq[2][64];
  __shared__ float preactF[1024];

  uint w[64];
  const uint* wrow = Wq + (long)d * 65536 + tid;
#pragma unroll
  for (int k4 = 0; k4 < 64; ++k4) w[k4] = wrow[k4 * 1024];
  // Force the 64 weight dwords to stay resident in VGPRs across the loop.
#pragma unroll
  for (int k4 = 0; k4 < 64; ++k4) asm volatile("" : "+v"(w[k4]));

  if (tid < 128) ((uint*)hq)[tid] = 0u;

  const float fsc = fscale[d * 1024 + tid] * (1.0f / 127.0f);
  const float* Xd = Xg + (long)d * 8192 * 1024;

  float c = 0.f;
  float x0 = 0.f, x1 = 0.f, x2 = 0.f, x3 = 0.f;
  if (tid < 256) {
    const float* xr = Xd + ((long)((d ? 127 : 0) * 64 + b)) * 1024;
    x0 = xr[tid]; x1 = xr[tid + 256]; x2 = xr[tid + 512]; x3 = xr[tid + 768];
  }
  __syncthreads();

  int cur = 0;
  for (int step = 0; step < 128; ++step) {
    const int t = d ? 127 - step : step;

    float n0 = 0.f, n1 = 0.f, n2 = 0.f, n3 = 0.f;
    if (tid < 256 && step + 1 < 128) {
      const float* xr = Xd + ((long)((d ? 126 - step : step + 1) * 64 + b)) * 1024;
      n0 = xr[tid]; n1 = xr[tid + 256]; n2 = xr[tid + 512]; n3 = xr[tid + 768];
    }

    int acc = 0;
    const uint4* hrow = (const uint4*)hq[cur];
#pragma unroll
    for (int k16 = 0; k16 < 16; ++k16) {
      uint4 h4 = hrow[k16];
      acc = sdot4_(w[k16 * 4 + 0], h4.x, acc);
      acc = sdot4_(w[k16 * 4 + 1], h4.y, acc);
      acc = sdot4_(w[k16 * 4 + 2], h4.z, acc);
      acc = sdot4_(w[k16 * 4 + 3], h4.w, acc);
    }
    preactF[tid] = (float)acc * fsc;
    __syncthreads();

    if (tid < 256) {
      float p0 = x0 + preactF[tid];
      float p1 = x1 + preactF[tid + 256];
      float p2 = x2 + preactF[tid + 512];
      float p3 = x3 + preactF[tid + 768];
      const float ig = fast_sig(p0), fg = fast_sig(p1);
      const float gg = fast_tanh(p2), og = fast_sig(p3);
      c = fg * c + ig * gg;
      const float h = og * fast_tanh(c);
      const long row = bmajor ? ((long)b * 128 + t) : ((long)t * 64 + b);
      out[row * 512 + (d << 8) + tid] = f2bf(h);
      ((char*)hq[cur ^ 1])[tid] = (char)__float2int_rn(h * 127.f);
      x0 = n0; x1 = n1; x2 = n2; x3 = n3;
    }
    __syncthreads();
    cur ^= 1;
  }
}

// W_rel basis combination -> bf16 transposed (N=r*256+o rows, K=f cols)
__global__ __launch_bounds__(256) void wrel_k(const float* __restrict__ basis,
                                              const float* __restrict__ comp,
                                              ushort* __restrict__ wrel2t) {
  const int f = blockIdx.x;     // 0..511
  const int o = threadIdx.x;    // 0..255
  __shared__ float cs[240];
  if (o < 240) cs[o] = comp[o];
  __syncthreads();
  float acc[8];
#pragma unroll
  for (int r = 0; r < 8; ++r) acc[r] = 0.f;
  for (int bb = 0; bb < 30; ++bb) {
    const float v = basis[((long)bb * 512 + f) * 256 + o];
#pragma unroll
    for (int r = 0; r < 8; ++r) acc[r] = fmaf(cs[r * 30 + bb], v, acc[r]);
  }
#pragma unroll
  for (int r = 0; r < 8; ++r)
    wrel2t[((long)(r * 256 + o)) * 512 + f] = f2bf(acc[r]);
}

// ---------------------------------------------------------------------------
// RGCN gather FUSED with edge-attention softmax (proven r11).
// ---------------------------------------------------------------------------
__global__ __launch_bounds__(256) void rgcn_fused_k(
    const float* __restrict__ scale, const ushort* __restrict__ xrel,
    const float* __restrict__ hroot, const int* __restrict__ spk,
    ushort* __restrict__ hbf)
{
  const int n = blockIdx.x;
  const int b = n >> 7, t = n & 127;
  const int o = threadIdx.x;
  const int lo = max(t - 10, 0), hi = min(t + 10, 127);
  const int cnt = hi - lo + 1;

  __shared__ float sc[128], red[128];
  __shared__ int spks[21];
  __shared__ int spkt_s;

  if (o < 128) {
    const float v = scale[((long)(b * 128 + o)) * 128 + t];
    sc[o] = v; red[o] = v;
  }
  if (o == 0) spkt_s = spk[t * 64 + b];
  if (o >= 128 && o - 128 < cnt) spks[o - 128] = spk[(lo + o - 128) * 64 + b];
  __syncthreads();
  for (int off = 64; off > 0; off >>= 1) {
    if (o < off) red[o] = fmaxf(red[o], red[o + off]);
    __syncthreads();
  }
  const float m = red[0];
  __syncthreads();
  if (o < 128) {
    const float e = expf(sc[o] - m);
    sc[o] = e;
    const int dd = o - t;
    const bool inwin = (dd <= 10) && (dd >= -10);
    red[o] = e * (inwin ? 1.0f : 1e-10f);
  }
  __syncthreads();
  for (int off = 64; off > 0; off >>= 1) {
    if (o < off) red[o] += red[o + off];
    __syncthreads();
  }
  const float inv_msum = 1.0f / red[0];
  __syncthreads();

  const int spkt = spkt_s;
  float acc = hroot[(long)n * 256 + o];
  for (int q = 0; q < cnt; ++q) {
    const int s = lo + q;
    const float wv = sc[s] * inv_msum;
    const int et = spkt * 4 + spks[q] * 2 + ((t < s) ? 0 : 1);
    acc = fmaf(bf2f(xrel[(((long)(b * 128 + s)) * 8 + et) * 256 + o]), wv, acc);
  }
  hbf[(long)n * 256 + o] = f2bf(acc);
}

// GraphConv neighbor aggregation (reads bf16 h) -> bf16
__global__ __launch_bounds__(256) void agg_k(const ushort* __restrict__ hbf,
                                             ushort* __restrict__ aggbf) {
  const int n = blockIdx.x;
  const int b = n >> 7, t = n & 127;
  const int o = threadIdx.x;
  const int lo = max(t - 10, 0), hi = min(t + 10, 127);
  float acc = 0.f;
  for (int s = lo; s <= hi; ++s) acc += bf2f(hbf[((long)(b * 128 + s)) * 256 + o]);
  aggbf[(long)n * 256 + o] = f2bf(acc);
}

// embf = concat(xbf, bf16(h2))
__global__ __launch_bounds__(256) void em_k(const ushort* __restrict__ xbf,
                                            const float* __restrict__ h2,
                                            ushort* __restrict__ embf) {
  const int n = blockIdx.x;
  const int tid = threadIdx.x;
  embf[(long)n * 768 + tid] = xbf[(long)n * 512 + tid];
  embf[(long)n * 768 + 256 + tid] = xbf[(long)n * 512 + 256 + tid];
  embf[(long)n * 768 + 512 + tid] = f2bf(h2[(long)n * 256 + tid]);
}

// Batched ushort transpose: dst[b](C x R) = src[b](R x C)^T, R=128, C=768.
__global__ __launch_bounds__(256) void emt_k(const ushort* __restrict__ src,
                                             ushort* __restrict__ dst) {
  __shared__ ushort tile[32][33];
  const int c0 = blockIdx.x * 32;
  const int r0 = blockIdx.y * 32;
  const int b = blockIdx.z;
  const ushort* s = src + (long)b * 98304;
  ushort* d = dst + (long)b * 98304;
  const int tx = threadIdx.x & 31, ty = threadIdx.x >> 5;
#pragma unroll
  for (int j = 0; j < 4; ++j)
    tile[ty + j * 8][tx] = s[(long)(r0 + ty + j * 8) * 768 + c0 + tx];
  __syncthreads();
#pragma unroll
  for (int j = 0; j < 4; ++j)
    d[(long)(c0 + ty + j * 8) * 128 + r0 + tx] = tile[tx][ty + j * 8];
}

// Matching attention probs: logits f32 in, bf16 a out
__global__ __launch_bounds__(128) void match_softmax_k(const float* __restrict__ logits,
                                                       const float* __restrict__ umask,
                                                       ushort* __restrict__ abf) {
  const int bx = blockIdx.x;           // b*128 + t
  const int b = bx >> 7;
  const int s = threadIdx.x;
  __shared__ float red[128];
  const float* row = logits + (long)bx * 128;
  const float um = umask[b * 128 + s];
  const float v = tanhf(row[s] * um * um);
  red[s] = v; __syncthreads();
  for (int off = 64; off > 0; off >>= 1) { if (s < off) red[s] = fmaxf(red[s], red[s + off]); __syncthreads(); }
  const float m = red[0]; __syncthreads();
  const float e = expf(v - m);
  red[s] = e; __syncthreads();
  for (int off = 64; off > 0; off >>= 1) { if (s < off) red[s] += red[s + off]; __syncthreads(); }
  const float es = red[0]; __syncthreads();
  const float p = (e / es) * um;
  red[s] = p; __syncthreads();
  for (int off = 64; off > 0; off >>= 1) { if (s < off) red[s] += red[s + off]; __syncthreads(); }
  const float ps = red[0];
  abf[(long)bx * 128 + s] = f2bf(p / ps);
}

__global__ __launch_bounds__(256) void final_k(const float* __restrict__ hidden,
                                               const float* __restrict__ Ws,
                                               const float* __restrict__ bs,
                                               float* __restrict__ out) {
  __shared__ float wsl[256 * 6];
  const int tid = threadIdx.x;
#pragma unroll
  for (int j = 0; j < 6; ++j) wsl[tid * 6 + j] = Ws[tid * 6 + j];
  __syncthreads();
  const int wave = tid >> 6, lane = tid & 63;
  const int n = blockIdx.x * 4 + wave;
  const float4 hv = *(const float4*)&hidden[(long)n * 256 + lane * 4];
  const float hvv[4] = {hv.x, hv.y, hv.z, hv.w};
  float a[6];
#pragma unroll
  for (int c = 0; c < 6; ++c) a[c] = 0.f;
#pragma unroll
  for (int j = 0; j < 4; ++j)
#pragma unroll
    for (int c = 0; c < 6; ++c)
      a[c] = fmaf(hvv[j], wsl[(lane * 4 + j) * 6 + c], a[c]);
#pragma unroll
  for (int off = 32; off > 0; off >>= 1)
#pragma unroll
    for (int c = 0; c < 6; ++c)
      a[c] += __shfl_xor(a[c], off, 64);
  if (lane == 0) {
    float v[6], m = -1e30f;
#pragma unroll
    for (int c = 0; c < 6; ++c) { v[c] = a[c] + bs[c]; m = fmaxf(m, v[c]); }
    float sum = 0.f;
#pragma unroll
    for (int c = 0; c < 6; ++c) sum += expf(v[c] - m);
    const float lse = m + logf(sum);
#pragma unroll
    for (int c = 0; c < 6; ++c) out[(long)n * 6 + c] = v[c] - lse;
  }
}

// ---------------------------------------------------------------------------
// Orchestration
// ---------------------------------------------------------------------------
extern "C" void kernel_launch(void* const* d_in, const int* in_sizes, int n_in,
                              void* d_out, int out_size, void* d_ws, size_t ws_size,
                              hipStream_t stream) {
  const float* U        = (const float*)d_in[0];
  const float* umask    = (const float*)d_in[1];
  const float* Wih0     = (const float*)d_in[2];
  const float* Whh0     = (const float*)d_in[3];
  const float* b0       = (const float*)d_in[4];
  const float* Wih1     = (const float*)d_in[5];
  const float* Whh1     = (const float*)d_in[6];
  const float* b1       = (const float*)d_in[7];
  const float* W_scalar = (const float*)d_in[8];
  const float* basis    = (const float*)d_in[9];
  const float* comp     = (const float*)d_in[10];
  const float* W_root   = (const float*)d_in[11];
  const float* b_rgcn   = (const float*)d_in[12];
  const float* gc_W1    = (const float*)d_in[13];
  const float* gc_W2    = (const float*)d_in[14];
  const float* gc_b     = (const float*)d_in[15];
  const float* Wm       = (const float*)d_in[16];
  const float* bm       = (const float*)d_in[17];
  const float* Wl       = (const float*)d_in[18];
  const float* bl       = (const float*)d_in[19];
  const float* Wsw      = (const float*)d_in[20];
  const float* bsw      = (const float*)d_in[21];
  const int*   speakers = (const int*)d_in[22];

  float* ws = (float*)d_ws;
  float* gates   = ws + 0L;          // 16.78M f: gates0/1 -> xrelbf -> xtrbf
  float* feats   = ws + 16777216L;   //  4.19M f: wih0bf/wih1bf -> attbf
  float* xbuf    = ws + 20971520L;   //  4.19M f: ubf -> xbf -> emT
  float* feats0  = ws + 25165824L;   //  4.19M f: f0bf -> hbf/aggbf -> embf
  float* scaleb  = ws + 29360128L;   //  1.05M f: scale -> logits -> hidden(lo)
  float* scoresb = ws + 30408704L;   //  1.05M f: wscT -> abf -> hidden(hi)
  float* wrelr   = ws + 31457280L;   //  1.05M f: wrel2t bf16
  float* hroot   = ws + 32505856L;   //  2.10M f: hroot -> h2
  uint*  wq      = (uint*)(ws + 34603008L);   // 262,144 dwords
  float* fsc     = ws + 34865152L;            // 4,096
  float* wTr     = ws + 34869248L;            // 524,288 f

  ushort* ubf    = (ushort*)xbuf;
  ushort* wih0bf = (ushort*)feats;
  ushort* wih1bf = (ushort*)(feats + 1048576L);
  ushort* f0bf   = (ushort*)feats0;
  ushort* xbf    = (ushort*)xbuf;
  ushort* wrel2t = (ushort*)wrelr;
  ushort* wroott = (ushort*)wTr;                 // 131,072 us
  ushort* gcW1t  = wroott + 131072L;             //  65,536 us
  ushort* gcW2t  = gcW1t + 65536L;               //  65,536 us
  ushort* Wmt    = gcW2t + 65536L;               // 589,824 us
  ushort* Wlt    = Wmt + 589824L;                // 196,608 us
  ushort* wscT   = (ushort*)scoresb;             // 65,536 us (dead after scale gemm)

  ushort* hbf     = (ushort*)(feats0 + 2097152L);
  ushort* aggbf   = (ushort*)(feats0 + 3145728L);
  ushort* embf    = (ushort*)feats0;
  ushort* emT     = (ushort*)xbuf;
  ushort* xrelbf  = (ushort*)gates;
  ushort* xtrbf   = (ushort*)gates;
  ushort* abf     = (ushort*)scoresb;
  ushort* attbf   = (ushort*)feats;

  float*  h2b     = hroot;
  float*  logitsb = scaleb;
  float*  hiddenb = scaleb;

  // --- weight prep (4 dispatches) ---
  pack_whh_all_k<<<1024, 256, 0, stream>>>(Whh0, Whh1, wq, fsc);
  cvt_all_k<<<11264, 256, 0, stream>>>(U, ubf, Wih0, wih0bf, Wih1, wih1bf);
  tp_all_k<<<1088, 256, 0, stream>>>(W_root, wroott, gc_W1, gcW1t, gc_W2, gcW2t,
                                     Wm, Wmt, Wl, Wlt, W_scalar, wscT);
  wrel_k<<<512, 256, 0, stream>>>(basis, comp, wrel2t);

  // --- layer 0 ---
  gemm_bf16_nt<true, false, false, false><<<dim3(8, 64, 2), 256, 0, stream>>>(
      ubf, wih0bf, b0, gates, 8192, 1024, 1024, 0L, 1048576L, 8388608L, 1024L);
  lstm4_k<<<128, 1024, 0, stream>>>(gates, wq, fsc, f0bf, 0);

  // --- layer 1 (writes x directly in b-major) ---
  gemm_bf16_nt<true, false, false, false><<<dim3(8, 64, 2), 256, 0, stream>>>(
      f0bf, wih1bf, b1, gates, 8192, 1024, 512, 0L, 524288L, 8388608L, 1024L);
  lstm4_k<<<128, 1024, 0, stream>>>(gates, wq + 131072, fsc + 2048, xbf, 1);

  // --- edge scale + RGCN ---
  gemm_bf16_nt<false, false, false, false><<<dim3(1, 64, 1), 256, 0, stream>>>(
      xbf, wscT, nullptr, scaleb, 8192, 128, 512, 0L, 0L, 0L, 0L);
  gemm_bf16_nt<true, false, false, false><<<dim3(2, 64, 1), 256, 0, stream>>>(
      xbf, wroott, b_rgcn, hroot, 8192, 256, 512, 0L, 0L, 0L, 0L);
  gemm_bf16_nt<false, false, false, true><<<dim3(16, 64, 1), 256, 0, stream>>>(
      xbf, wrel2t, nullptr, xrelbf, 8192, 2048, 512, 0L, 0L, 0L, 0L);
  rgcn_fused_k<<<8192, 256, 0, stream>>>(scaleb, xrelbf, hroot, speakers, hbf);

  // --- GraphConv ---
  agg_k<<<8192, 256, 0, stream>>>(hbf, aggbf);
  gemm_bf16_nt<true, false, false, false><<<dim3(2, 64, 1), 256, 0, stream>>>(
      hbf, gcW1t, gc_b, h2b, 8192, 256, 256, 0L, 0L, 0L, 0L);
  gemm_bf16_nt<false, true, false, false><<<dim3(2, 64, 1), 256, 0, stream>>>(
      aggbf, gcW2t, nullptr, h2b, 8192, 256, 256, 0L, 0L, 0L, 0L);

  // --- matching attention ---
  em_k<<<8192, 256, 0, stream>>>(xbf, h2b, embf);
  gemm_bf16_nt<true, false, false, true><<<dim3(6, 64, 1), 256, 0, stream>>>(
      embf, Wmt, bm, xtrbf, 8192, 768, 768, 0L, 0L, 0L, 0L);
  emt_k<<<dim3(24, 4, 64), 256, 0, stream>>>(embf, emT);
  gemm_bf16_nt<false, false, false, false><<<dim3(1, 1, 64), 256, 0, stream>>>(
      xtrbf, embf, nullptr, logitsb, 128, 128, 768, 98304L, 98304L, 16384L, 0L);
  match_softmax_k<<<8192, 128, 0, stream>>>(logitsb, umask, abf);
  gemm_bf16_nt<false, false, false, true><<<dim3(6, 1, 64), 256, 0, stream>>>(
      abf, emT, nullptr, attbf, 128, 768, 128, 16384L, 98304L, 98304L, 0L);

  // --- classifier ---
  gemm_bf16_nt<true, false, true, false><<<dim3(2, 64, 1), 256, 0, stream>>>(
      attbf, Wlt, bl, hiddenb, 8192, 256, 768, 0L, 0L, 0L, 0L);
  final_k<<<2048, 256, 0, stream>>>(hiddenb, Wsw, bsw, (float*)d_out);
}

// Round 13
// 611.285 us; speedup vs baseline: 1.3855x; 1.0173x over previous
//
#include <hip/hip_runtime.h>
#include <cstdint>

// Model dims (fixed): L=128, B=64, DM=1024, H=256, F=512, HID=256, MEM=768,
// N=B*L=8192, NC=6, R=8, NB=30, WIN=10

typedef __attribute__((ext_vector_type(8))) short bf16x8;
typedef __attribute__((ext_vector_type(4))) float f32x4;

__device__ __forceinline__ void gload_lds16(const void* g, void* l) {
  __builtin_amdgcn_global_load_lds(
      (const __attribute__((address_space(1))) void*)g,
      (__attribute__((address_space(3))) void*)l, 16, 0, 0);
}

// ---------------------------------------------------------------------------
// bf16 NT MFMA GEMM: C(MxN) = A(MxK)bf16 @ Bt(NxK)bf16^T (+bias)(+accum)
// A row stride lda, C row stride ldc (B row stride == K). Batched via
// blockIdx.z. 128x128x32 tile, 4 waves, 16x16x32 MFMA, global_load_lds.
// ---------------------------------------------------------------------------
template<bool HASBIAS, bool ACCUM, bool RELU, bool OUTBF>
__global__ __launch_bounds__(256) void gemm_bf16_nt(
    const ushort* __restrict__ A, const ushort* __restrict__ Bt,
    const float* __restrict__ bias, void* __restrict__ Cv,
    int M, int N, int K, long lda, long ldc,
    long sA, long sB, long sC, long sBias)
{
  const int bz = blockIdx.z;
  A += (long)bz * sA;
  Bt += (long)bz * sB;
  if (HASBIAS) bias += (long)bz * sBias;
  float*  Cf = OUTBF ? nullptr : ((float*)Cv + (long)bz * sC);
  ushort* Cb = OUTBF ? ((ushort*)Cv + (long)bz * sC) : nullptr;

  const int bn = blockIdx.x * 128, bm = blockIdx.y * 128;

  __shared__ ushort As[128][32];
  __shared__ ushort Bs[128][32];

  const int tid = threadIdx.x;
  const int wave = tid >> 6, lane = tid & 63;
  const int wm = (wave >> 1) * 64, wn = (wave & 1) * 64;
  const int fr = lane & 15;
  const int fk = (lane >> 4) * 8;

  f32x4 acc[4][4];
#pragma unroll
  for (int i = 0; i < 4; ++i)
#pragma unroll
    for (int j = 0; j < 4; ++j) acc[i][j] = (f32x4){0.f, 0.f, 0.f, 0.f};

  const int f0 = wave * 2 * 64 + lane;
  const int f1 = f0 + 64;
  const int r0 = f0 >> 2, c0 = (f0 & 3) * 8;
  const int r1 = f1 >> 2, c1 = (f1 & 3) * 8;
  ushort* As0 = (ushort*)As + wave * 2 * 512;
  ushort* As1 = As0 + 512;
  ushort* Bs0 = (ushort*)Bs + wave * 2 * 512;
  ushort* Bs1 = Bs0 + 512;

  for (int k0 = 0; k0 < K; k0 += 32) {
    gload_lds16(A + (long)(bm + r0) * lda + k0 + c0, As0);
    gload_lds16(A + (long)(bm + r1) * lda + k0 + c1, As1);
    gload_lds16(Bt + (long)(bn + r0) * K + k0 + c0, Bs0);
    gload_lds16(Bt + (long)(bn + r1) * K + k0 + c1, Bs1);
    __syncthreads();

    bf16x8 af[4], bfr[4];
#pragma unroll
    for (int f = 0; f < 4; ++f) {
      af[f]  = *(const bf16x8*)&As[wm + f * 16 + fr][fk];
      bfr[f] = *(const bf16x8*)&Bs[wn + f * 16 + fr][fk];
    }
#pragma unroll
    for (int mf = 0; mf < 4; ++mf)
#pragma unroll
      for (int nf = 0; nf < 4; ++nf)
        acc[mf][nf] = __builtin_amdgcn_mfma_f32_16x16x32_bf16(
            af[mf], bfr[nf], acc[mf][nf], 0, 0, 0);
    __syncthreads();
  }

  float bv[4];
#pragma unroll
  for (int nf = 0; nf < 4; ++nf)
    bv[nf] = HASBIAS ? bias[bn + wn + nf * 16 + fr] : 0.f;

  const int crow0 = (lane >> 4) * 4;
#pragma unroll
  for (int mf = 0; mf < 4; ++mf)
#pragma unroll
    for (int r = 0; r < 4; ++r) {
      const long roff = (long)(bm + wm + mf * 16 + crow0 + r) * ldc + bn + wn;
#pragma unroll
      for (int nf = 0; nf < 4; ++nf) {
        float v = acc[mf][nf][r] + bv[nf];
        if (OUTBF) {
          unsigned u = __float_as_uint(v);
          u += 0x7fffu + ((u >> 16) & 1u);
          Cb[roff + nf * 16 + fr] = (ushort)(u >> 16);
        } else {
          if (ACCUM) v += Cf[roff + nf * 16 + fr];
          if (RELU) v = fmaxf(v, 0.f);
          Cf[roff + nf * 16 + fr] = v;
        }
      }
    }
}

// ---------------------------------------------------------------------------
// helpers
// ---------------------------------------------------------------------------
__device__ __forceinline__ unsigned short f2bf(float f) {
  unsigned u = __float_as_uint(f);
  u += 0x7fffu + ((u >> 16) & 1u);
  return (unsigned short)(u >> 16);
}
__device__ __forceinline__ float bf2f(ushort v) {
  return __uint_as_float(((unsigned)v) << 16);
}
__device__ __forceinline__ float fast_sig(float x) {
  return __builtin_amdgcn_rcpf(1.f + __expf(-x));
}
__device__ __forceinline__ float fast_tanh(float x) {
  return 2.f * fast_sig(2.f * x) - 1.f;
}

__device__ __forceinline__ int sdot4_(uint a, uint b, int c) {
#if __has_builtin(__builtin_amdgcn_sdot4)
  return __builtin_amdgcn_sdot4((int)a, (int)b, c, false);
#else
  int r = c;
  r += ((int)(a << 24) >> 24) * ((int)(b << 24) >> 24);
  r += ((int)(a << 16) >> 24) * ((int)(b << 16) >> 24);
  r += ((int)(a << 8)  >> 24) * ((int)(b << 8)  >> 24);
  r += ((int)a >> 24)         * ((int)b >> 24);
  return r;
#endif
}

// Fused f32->bf16 conversions: U (8192 blocks) + Wih0 (2048) + Wih1 (1024)
__global__ __launch_bounds__(256) void cvt_all_k(
    const float* __restrict__ U, ushort* __restrict__ ubf,
    const float* __restrict__ W0, ushort* __restrict__ w0,
    const float* __restrict__ W1, ushort* __restrict__ w1)
{
  const int bid = blockIdx.x;
  const float* src; ushort* dst; long base;
  if (bid < 8192)       { src = U;  dst = ubf; base = (long)bid * 1024; }
  else if (bid < 10240) { src = W0; dst = w0;  base = (long)(bid - 8192) * 1024; }
  else                  { src = W1; dst = w1;  base = (long)(bid - 10240) * 1024; }
  const long i = base + threadIdx.x * 4;
  float4 v = *(const float4*)(src + i);
  ushort4 o;
  o.x = f2bf(v.x); o.y = f2bf(v.y); o.z = f2bf(v.z); o.w = f2bf(v.w);
  *(ushort4*)(dst + i) = o;
}

// Fused transpose+bf16 for the weight matrices. Each job: dst[c*dstStride +
// dstOff + r] = src[r*C + c]. gc_W1/gc_W2 stack into one 256x512 matrix.
__global__ __launch_bounds__(256) void tp_all_k(
    const float* __restrict__ s0, ushort* __restrict__ d0,   // W_root 512x256
    const float* __restrict__ s1, const float* __restrict__ s2,
    ushort* __restrict__ d12,                                // gc stacked 256x512
    const float* __restrict__ s3, ushort* __restrict__ d3,   // Wm 768x768
    const float* __restrict__ s4, ushort* __restrict__ d4,   // Wl 768x256
    const float* __restrict__ s5, ushort* __restrict__ d5)   // W_scalar 512x128
{
  __shared__ float tile[32][33];
  const int bid = blockIdx.x;
  const float* src; ushort* dst; int C, gx, local, dstStride, dstOff;
  if (bid < 128)       { src = s0; dst = d0;  C = 256; gx = 8;  local = bid;        dstStride = 512; dstOff = 0; }
  else if (bid < 192)  { src = s1; dst = d12; C = 256; gx = 8;  local = bid - 128;  dstStride = 512; dstOff = 0; }
  else if (bid < 256)  { src = s2; dst = d12; C = 256; gx = 8;  local = bid - 192;  dstStride = 512; dstOff = 256; }
  else if (bid < 832)  { src = s3; dst = d3;  C = 768; gx = 24; local = bid - 256;  dstStride = 768; dstOff = 0; }
  else if (bid < 1024) { src = s4; dst = d4;  C = 256; gx = 8;  local = bid - 832;  dstStride = 768; dstOff = 0; }
  else                 { src = s5; dst = d5;  C = 128; gx = 4;  local = bid - 1024; dstStride = 512; dstOff = 0; }
  const int c0 = (local % gx) * 32, r0 = (local / gx) * 32;
  const int tx = threadIdx.x & 31, ty = threadIdx.x >> 5;
#pragma unroll
  for (int j = 0; j < 4; ++j)
    tile[ty + j * 8][tx] = src[(long)(r0 + ty + j * 8) * C + c0 + tx];
  __syncthreads();
#pragma unroll
  for (int j = 0; j < 4; ++j)
    dst[(long)(c0 + ty + j * 8) * dstStride + dstOff + r0 + tx] = f2bf(tile[tx][ty + j * 8]);
}

// Fused Whh pack (both layers): (2,1024,256) f32 -> int8 dwords + scales
__global__ __launch_bounds__(256) void pack_whh_all_k(
    const float* __restrict__ Whh0, const float* __restrict__ Whh1,
    uint* __restrict__ Wq, float* __restrict__ fscale)
{
  const int wid = (blockIdx.x * 256 + threadIdx.x) >> 6;  // 0..4095
  const int lane = threadIdx.x & 63;
  const int l = wid >> 11;
  const int wid2 = wid & 2047;
  const int d = wid2 >> 10, gi = wid2 & 1023;
  const float* Whh = l ? Whh1 : Whh0;
  const float* row = Whh + ((long)d * 1024 + gi) * 256 + lane * 4;
  float v0 = row[0], v1 = row[1], v2 = row[2], v3 = row[3];
  float am = fmaxf(fmaxf(fabsf(v0), fabsf(v1)), fmaxf(fabsf(v2), fabsf(v3)));
#pragma unroll
  for (int off = 32; off > 0; off >>= 1) am = fmaxf(am, __shfl_xor(am, off, 64));
  am = fmaxf(am, 1e-12f);
  const float inv = 127.f / am;
  int q0 = __float2int_rn(v0 * inv), q1 = __float2int_rn(v1 * inv);
  int q2 = __float2int_rn(v2 * inv), q3 = __float2int_rn(v3 * inv);
  uint w = (uint)(q0 & 255) | ((uint)(q1 & 255) << 8) |
           ((uint)(q2 & 255) << 16) | ((uint)(q3 & 255) << 24);
  Wq[(long)l * 131072 + ((long)d * 64 + lane) * 1024 + gi] = w;
  if (lane == 0) fscale[l * 2048 + d * 1024 + gi] = am / 127.f;
}

// ---------------------------------------------------------------------------
// LSTM v4 (proven, at L2-BW roofline): int8 weights streamed from L2, int8 h
// via LDS broadcast, sdot4; bf16 output with row stride ldo.
// ---------------------------------------------------------------------------
__global__ __launch_bounds__(1024) void lstm4_k(
    const float* __restrict__ Xg,
    const uint* __restrict__ Wq,
    const float* __restrict__ fscale,
    ushort* __restrict__ out,
    int bmajor, long ldo)
{
  const int bx = blockIdx.x;
  const int d = bx >> 6, b = bx & 63;
  const int tid = threadIdx.x;

  __shared__ uint hq[2][64];
  __shared__ float preactF[1024];

  uint w[64];
  const uint* wrow = Wq + (long)d * 65536 + tid;
#pragma unroll
  for (int k4 = 0; k4 < 64; ++k4) w[k4] = wrow[k4 * 1024];

  if (tid < 128) ((uint*)hq)[tid] = 0u;

  const float fsc = fscale[d * 1024 + tid] * (1.0f / 127.0f);
  const float* Xd = Xg + (long)d * 8192 * 1024;

  float c = 0.f;
  float x0 = 0.f, x1 = 0.f, x2 = 0.f, x3 = 0.f;
  if (tid < 256) {
    const float* xr = Xd + ((long)((d ? 127 : 0) * 64 + b)) * 1024;
    x0 = xr[tid]; x1 = xr[tid + 256]; x2 = xr[tid + 512]; x3 = xr[tid + 768];
  }
  __syncthreads();

  int cur = 0;
  for (int step = 0; step < 128; ++step) {
    const int t = d ? 127 - step : step;

    float n0 = 0.f, n1 = 0.f, n2 = 0.f, n3 = 0.f;
    if (tid < 256 && step + 1 < 128) {
      const float* xr = Xd + ((long)((d ? 126 - step : step + 1) * 64 + b)) * 1024;
      n0 = xr[tid]; n1 = xr[tid + 256]; n2 = xr[tid + 512]; n3 = xr[tid + 768];
    }

    int acc = 0;
    const uint4* hrow = (const uint4*)hq[cur];
#pragma unroll
    for (int k16 = 0; k16 < 16; ++k16) {
      uint4 h4 = hrow[k16];
      acc = sdot4_(w[k16 * 4 + 0], h4.x, acc);
      acc = sdot4_(w[k16 * 4 + 1], h4.y, acc);
      acc = sdot4_(w[k16 * 4 + 2], h4.z, acc);
      acc = sdot4_(w[k16 * 4 + 3], h4.w, acc);
    }
    preactF[tid] = (float)acc * fsc;
    __syncthreads();

    if (tid < 256) {
      float p0 = x0 + preactF[tid];
      float p1 = x1 + preactF[tid + 256];
      float p2 = x2 + preactF[tid + 512];
      float p3 = x3 + preactF[tid + 768];
      const float ig = fast_sig(p0), fg = fast_sig(p1);
      const float gg = fast_tanh(p2), og = fast_sig(p3);
      c = fg * c + ig * gg;
      const float h = og * fast_tanh(c);
      const long row = bmajor ? ((long)b * 128 + t) : ((long)t * 64 + b);
      out[row * ldo + (d << 8) + tid] = f2bf(h);
      ((char*)hq[cur ^ 1])[tid] = (char)__float2int_rn(h * 127.f);
      x0 = n0; x1 = n1; x2 = n2; x3 = n3;
    }
    __syncthreads();
    cur ^= 1;
  }
}

// W_rel basis combination -> bf16 transposed (N=r*256+o rows, K=f cols)
__global__ __launch_bounds__(256) void wrel_k(const float* __restrict__ basis,
                                              const float* __restrict__ comp,
                                              ushort* __restrict__ wrel2t) {
  const int f = blockIdx.x;     // 0..511
  const int o = threadIdx.x;    // 0..255
  __shared__ float cs[240];
  if (o < 240) cs[o] = comp[o];
  __syncthreads();
  float acc[8];
#pragma unroll
  for (int r = 0; r < 8; ++r) acc[r] = 0.f;
  for (int bb = 0; bb < 30; ++bb) {
    const float v = basis[((long)bb * 512 + f) * 256 + o];
#pragma unroll
    for (int r = 0; r < 8; ++r) acc[r] = fmaf(cs[r * 30 + bb], v, acc[r]);
  }
#pragma unroll
  for (int r = 0; r < 8; ++r)
    wrel2t[((long)(r * 256 + o)) * 512 + f] = f2bf(acc[r]);
}

// ---------------------------------------------------------------------------
// RGCN gather FUSED with edge-attention softmax (proven r11). Writes the h
// half of the [8192][512] {h|agg} buffer.
// ---------------------------------------------------------------------------
__global__ __launch_bounds__(256) void rgcn_fused_k(
    const float* __restrict__ scale, const ushort* __restrict__ xrel,
    const float* __restrict__ hroot, const int* __restrict__ spk,
    ushort* __restrict__ hagg)
{
  const int n = blockIdx.x;
  const int b = n >> 7, t = n & 127;
  const int o = threadIdx.x;
  const int lo = max(t - 10, 0), hi = min(t + 10, 127);
  const int cnt = hi - lo + 1;

  __shared__ float sc[128], red[128];
  __shared__ int spks[21];
  __shared__ int spkt_s;

  if (o < 128) {
    const float v = scale[((long)(b * 128 + o)) * 128 + t];
    sc[o] = v; red[o] = v;
  }
  if (o == 0) spkt_s = spk[t * 64 + b];
  if (o >= 128 && o - 128 < cnt) spks[o - 128] = spk[(lo + o - 128) * 64 + b];
  __syncthreads();
  for (int off = 64; off > 0; off >>= 1) {
    if (o < off) red[o] = fmaxf(red[o], red[o + off]);
    __syncthreads();
  }
  const float m = red[0];
  __syncthreads();
  if (o < 128) {
    const float e = expf(sc[o] - m);
    sc[o] = e;
    const int dd = o - t;
    const bool inwin = (dd <= 10) && (dd >= -10);
    red[o] = e * (inwin ? 1.0f : 1e-10f);
  }
  __syncthreads();
  for (int off = 64; off > 0; off >>= 1) {
    if (o < off) red[o] += red[o + off];
    __syncthreads();
  }
  const float inv_msum = 1.0f / red[0];
  __syncthreads();

  const int spkt = spkt_s;
  float acc = hroot[(long)n * 256 + o];
  for (int q = 0; q < cnt; ++q) {
    const int s = lo + q;
    const float wv = sc[s] * inv_msum;
    const int et = spkt * 4 + spks[q] * 2 + ((t < s) ? 0 : 1);
    acc = fmaf(bf2f(xrel[(((long)(b * 128 + s)) * 8 + et) * 256 + o]), wv, acc);
  }
  hagg[(long)n * 512 + o] = f2bf(acc);
}

// GraphConv neighbor aggregation: reads h half, writes agg half (cols 256+)
__global__ __launch_bounds__(256) void agg_k(ushort* __restrict__ hagg) {
  const int n = blockIdx.x;
  const int b = n >> 7, t = n & 127;
  const int o = threadIdx.x;
  const int lo = max(t - 10, 0), hi = min(t + 10, 127);
  float acc = 0.f;
  for (int s = lo; s <= hi; ++s) acc += bf2f(hagg[((long)(b * 128 + s)) * 512 + o]);
  hagg[(long)n * 512 + 256 + o] = f2bf(acc);
}

// Batched ushort transpose: dst[b](C x R) = src[b](R x C)^T, R=128, C=768.
__global__ __launch_bounds__(256) void emt_k(const ushort* __restrict__ src,
                                             ushort* __restrict__ dst) {
  __shared__ ushort tile[32][33];
  const int c0 = blockIdx.x * 32;
  const int r0 = blockIdx.y * 32;
  const int b = blockIdx.z;
  const ushort* s = src + (long)b * 98304;
  ushort* d = dst + (long)b * 98304;
  const int tx = threadIdx.x & 31, ty = threadIdx.x >> 5;
#pragma unroll
  for (int j = 0; j < 4; ++j)
    tile[ty + j * 8][tx] = s[(long)(r0 + ty + j * 8) * 768 + c0 + tx];
  __syncthreads();
#pragma unroll
  for (int j = 0; j < 4; ++j)
    d[(long)(c0 + ty + j * 8) * 128 + r0 + tx] = tile[tx][ty + j * 8];
}

// Matching attention probs: logits f32 in, bf16 a out
__global__ __launch_bounds__(128) void match_softmax_k(const float* __restrict__ logits,
                                                       const float* __restrict__ umask,
                                                       ushort* __restrict__ abf) {
  const int bx = blockIdx.x;           // b*128 + t
  const int b = bx >> 7;
  const int s = threadIdx.x;
  __shared__ float red[128];
  const float* row = logits + (long)bx * 128;
  const float um = umask[b * 128 + s];
  const float v = tanhf(row[s] * um * um);
  red[s] = v; __syncthreads();
  for (int off = 64; off > 0; off >>= 1) { if (s < off) red[s] = fmaxf(red[s], red[s + off]); __syncthreads(); }
  const float m = red[0]; __syncthreads();
  const float e = expf(v - m);
  red[s] = e; __syncthreads();
  for (int off = 64; off > 0; off >>= 1) { if (s < off) red[s] += red[s + off]; __syncthreads(); }
  const float es = red[0]; __syncthreads();
  const float p = (e / es) * um;
  red[s] = p; __syncthreads();
  for (int off = 64; off > 0; off >>= 1) { if (s < off) red[s] += red[s + off]; __syncthreads(); }
  const float ps = red[0];
  abf[(long)bx * 128 + s] = f2bf(p / ps);
}

__global__ __launch_bounds__(256) void final_k(const float* __restrict__ hidden,
                                               const float* __restrict__ Ws,
                                               const float* __restrict__ bs,
                                               float* __restrict__ out) {
  __shared__ float wsl[256 * 6];
  const int tid = threadIdx.x;
#pragma unroll
  for (int j = 0; j < 6; ++j) wsl[tid * 6 + j] = Ws[tid * 6 + j];
  __syncthreads();
  const int wave = tid >> 6, lane = tid & 63;
  const int n = blockIdx.x * 4 + wave;
  const float4 hv = *(const float4*)&hidden[(long)n * 256 + lane * 4];
  const float hvv[4] = {hv.x, hv.y, hv.z, hv.w};
  float a[6];
#pragma unroll
  for (int c = 0; c < 6; ++c) a[c] = 0.f;
#pragma unroll
  for (int j = 0; j < 4; ++j)
#pragma unroll
    for (int c = 0; c < 6; ++c)
      a[c] = fmaf(hvv[j], wsl[(lane * 4 + j) * 6 + c], a[c]);
#pragma unroll
  for (int off = 32; off > 0; off >>= 1)
#pragma unroll
    for (int c = 0; c < 6; ++c)
      a[c] += __shfl_xor(a[c], off, 64);
  if (lane == 0) {
    float v[6], m = -1e30f;
#pragma unroll
    for (int c = 0; c < 6; ++c) { v[c] = a[c] + bs[c]; m = fmaxf(m, v[c]); }
    float sum = 0.f;
#pragma unroll
    for (int c = 0; c < 6; ++c) sum += expf(v[c] - m);
    const float lse = m + logf(sum);
#pragma unroll
    for (int c = 0; c < 6; ++c) out[(long)n * 6 + c] = v[c] - lse;
  }
}

// ---------------------------------------------------------------------------
// Orchestration
// ---------------------------------------------------------------------------
extern "C" void kernel_launch(void* const* d_in, const int* in_sizes, int n_in,
                              void* d_out, int out_size, void* d_ws, size_t ws_size,
                              hipStream_t stream) {
  const float* U        = (const float*)d_in[0];
  const float* umask    = (const float*)d_in[1];
  const float* Wih0     = (const float*)d_in[2];
  const float* Whh0     = (const float*)d_in[3];
  const float* b0       = (const float*)d_in[4];
  const float* Wih1     = (const float*)d_in[5];
  const float* Whh1     = (const float*)d_in[6];
  const float* b1       = (const float*)d_in[7];
  const float* W_scalar = (const float*)d_in[8];
  const float* basis    = (const float*)d_in[9];
  const float* comp     = (const float*)d_in[10];
  const float* W_root   = (const float*)d_in[11];
  const float* b_rgcn   = (const float*)d_in[12];
  const float* gc_W1    = (const float*)d_in[13];
  const float* gc_W2    = (const float*)d_in[14];
  const float* gc_b     = (const float*)d_in[15];
  const float* Wm       = (const float*)d_in[16];
  const float* bm       = (const float*)d_in[17];
  const float* Wl       = (const float*)d_in[18];
  const float* bl       = (const float*)d_in[19];
  const float* Wsw      = (const float*)d_in[20];
  const float* bsw      = (const float*)d_in[21];
  const int*   speakers = (const int*)d_in[22];

  float* ws = (float*)d_ws;
  // Regions (float offsets), lifetimes audited:
  float* gates   = ws + 0L;          // 16.78M f: gates0/1 -> xrelbf -> xtrbf
  float* feats   = ws + 16777216L;   //  4.19M f: wih0bf/wih1bf -> attbf
  float* xbuf    = ws + 20971520L;   //  4.19M f: ubf -> hagg -> emT
  float* feats0  = ws + 25165824L;   //  4.19M f: f0bf -> xemb [8192][768]
  float* scaleb  = ws + 29360128L;   //  1.05M f: scale -> logits -> hidden(lo)
  float* scoresb = ws + 30408704L;   //  1.05M f: wscT -> abf -> hidden(hi)
  float* wrelr   = ws + 31457280L;   //  1.05M f: wrel2t bf16
  float* hroot   = ws + 32505856L;   //  2.10M f: hroot f32
  uint*  wq      = (uint*)(ws + 34603008L);   // 262,144 dwords
  float* fsc     = ws + 34865152L;            // 4,096
  float* wTr     = ws + 34869248L;            // 524,288 f (transposed weights)

  ushort* ubf    = (ushort*)xbuf;
  ushort* wih0bf = (ushort*)feats;
  ushort* wih1bf = (ushort*)(feats + 1048576L);
  ushort* f0bf   = (ushort*)feats0;              // dead after gates L1 gemm
  ushort* xemb   = (ushort*)feats0;              // [8192][768]: x | gc-out
  ushort* wrel2t = (ushort*)wrelr;
  ushort* wroott = (ushort*)wTr;                 // 131,072 us (256 x 512)
  ushort* gcW12t = wroott + 131072L;             // 131,072 us (256 x 512 stacked)
  ushort* Wmt    = gcW12t + 131072L;             // 589,824 us
  ushort* Wlt    = Wmt + 589824L;                // 196,608 us
  ushort* wscT   = (ushort*)scoresb;             // 65,536 us (dead after scale gemm)

  ushort* hagg    = (ushort*)xbuf;               // [8192][512]: h | agg (ubf dead)
  ushort* emT     = (ushort*)xbuf;               // after gc gemm (hagg dead)
  ushort* xrelbf  = (ushort*)gates;
  ushort* xtrbf   = (ushort*)gates;
  ushort* abf     = (ushort*)scoresb;
  ushort* attbf   = (ushort*)feats;

  float*  logitsb = scaleb;
  float*  hiddenb = scaleb;

  // --- weight prep (4 dispatches) ---
  pack_whh_all_k<<<1024, 256, 0, stream>>>(Whh0, Whh1, wq, fsc);
  cvt_all_k<<<11264, 256, 0, stream>>>(U, ubf, Wih0, wih0bf, Wih1, wih1bf);
  tp_all_k<<<1088, 256, 0, stream>>>(W_root, wroott, gc_W1, gc_W2, gcW12t,
                                     Wm, Wmt, Wl, Wlt, W_scalar, wscT);
  wrel_k<<<512, 256, 0, stream>>>(basis, comp, wrel2t);

  // --- layer 0 ---
  gemm_bf16_nt<true, false, false, false><<<dim3(8, 64, 2), 256, 0, stream>>>(
      ubf, wih0bf, b0, gates, 8192, 1024, 1024, 1024L, 1024L,
      0L, 1048576L, 8388608L, 1024L);
  lstm4_k<<<128, 1024, 0, stream>>>(gates, wq, fsc, f0bf, 0, 512L);

  // --- layer 1 (writes x directly into xemb cols [0:512), b-major) ---
  gemm_bf16_nt<true, false, false, false><<<dim3(8, 64, 2), 256, 0, stream>>>(
      f0bf, wih1bf, b1, gates, 8192, 1024, 512, 512L, 1024L,
      0L, 524288L, 8388608L, 1024L);
  lstm4_k<<<128, 1024, 0, stream>>>(gates, wq + 131072, fsc + 2048, xemb, 1, 768L);

  // --- edge scale + RGCN ---
  gemm_bf16_nt<false, false, false, false><<<dim3(1, 64, 1), 256, 0, stream>>>(
      xemb, wscT, nullptr, scaleb, 8192, 128, 512, 768L, 128L, 0L, 0L, 0L, 0L);
  gemm_bf16_nt<true, false, false, false><<<dim3(2, 64, 1), 256, 0, stream>>>(
      xemb, wroott, b_rgcn, hroot, 8192, 256, 512, 768L, 256L, 0L, 0L, 0L, 0L);
  gemm_bf16_nt<false, false, false, true><<<dim3(16, 64, 1), 256, 0, stream>>>(
      xemb, wrel2t, nullptr, xrelbf, 8192, 2048, 512, 768L, 2048L, 0L, 0L, 0L, 0L);
  rgcn_fused_k<<<8192, 256, 0, stream>>>(scaleb, xrelbf, hroot, speakers, hagg);

  // --- GraphConv (merged: [h|agg] @ [W1;W2] + b -> xemb cols [512:768)) ---
  agg_k<<<8192, 256, 0, stream>>>(hagg);
  gemm_bf16_nt<true, false, false, true><<<dim3(2, 64, 1), 256, 0, stream>>>(
      hagg, gcW12t, gc_b, xemb + 512, 8192, 256, 512, 512L, 768L, 0L, 0L, 0L, 0L);

  // --- matching attention ---
  gemm_bf16_nt<true, false, false, true><<<dim3(6, 64, 1), 256, 0, stream>>>(
      xemb, Wmt, bm, xtrbf, 8192, 768, 768, 768L, 768L, 0L, 0L, 0L, 0L);
  emt_k<<<dim3(24, 4, 64), 256, 0, stream>>>(xemb, emT);
  gemm_bf16_nt<false, false, false, false><<<dim3(1, 1, 64), 256, 0, stream>>>(
      xtrbf, xemb, nullptr, logitsb, 128, 128, 768, 768L, 128L,
      98304L, 98304L, 16384L, 0L);
  match_softmax_k<<<8192, 128, 0, stream>>>(logitsb, umask, abf);
  gemm_bf16_nt<false, false, false, true><<<dim3(6, 1, 64), 256, 0, stream>>>(
      abf, emT, nullptr, attbf, 128, 768, 128, 128L, 768L,
      16384L, 98304L, 98304L, 0L);

  // --- classifier ---
  gemm_bf16_nt<true, false, true, false><<<dim3(2, 64, 1), 256, 0, stream>>>(
      attbf, Wlt, bl, hiddenb, 8192, 256, 768, 768L, 256L, 0L, 0L, 0L, 0L);
  final_k<<<2048, 256, 0, stream>>>(hiddenb, Wsw, bsw, (float*)d_out);
}